// Round 1
// baseline (2488.211 us; speedup 1.0000x reference)
//
#include <hip/hip_runtime.h>
#include <math.h>

#define LSEQ 2048
#define DM 512
#define DI 1024
#define NST 16

__device__ __forceinline__ float siluf(float v) { return v / (1.f + expf(-v)); }

// ---------------- generic fp32 GEMM: C[M,N] = A[M,K] @ B[K,N] (+C if accum) -----
// 64x64 tile, 256 threads, 4x4 micro-tile per thread, BK=16. M,N multiples of 64,
// K multiple of 16, lda/ldb/ldc multiples of 4.
__global__ __launch_bounds__(256) void gemm64(
    const float* __restrict__ A, int lda,
    const float* __restrict__ B, int ldb,
    float* __restrict__ C, int ldc,
    int K, int accum)
{
    __shared__ float As[16][68];
    __shared__ float Bs[16][68];
    const int tid = threadIdx.x;
    const int tx = tid & 15, ty = tid >> 4;
    const int m0 = blockIdx.y << 6, n0 = blockIdx.x << 6;
    const int arow = tid >> 2, akk = (tid & 3) << 2;
    const int bkr = tid >> 4, bnn = (tid & 15) << 2;
    const float* Ap = A + (size_t)(m0 + arow) * lda + akk;
    const float* Bp = B + (size_t)bkr * ldb + n0 + bnn;
    float acc[4][4] = {};
    for (int k0 = 0; k0 < K; k0 += 16) {
        float4 av = *(const float4*)(Ap + k0);
        float4 bv = *(const float4*)(Bp + (size_t)k0 * ldb);
        As[akk + 0][arow] = av.x;
        As[akk + 1][arow] = av.y;
        As[akk + 2][arow] = av.z;
        As[akk + 3][arow] = av.w;
        *(float4*)&Bs[bkr][bnn] = bv;
        __syncthreads();
#pragma unroll
        for (int kk = 0; kk < 16; ++kk) {
            float4 a = *(const float4*)&As[kk][ty << 2];
            float4 b = *(const float4*)&Bs[kk][tx << 2];
            acc[0][0] = fmaf(a.x, b.x, acc[0][0]);
            acc[0][1] = fmaf(a.x, b.y, acc[0][1]);
            acc[0][2] = fmaf(a.x, b.z, acc[0][2]);
            acc[0][3] = fmaf(a.x, b.w, acc[0][3]);
            acc[1][0] = fmaf(a.y, b.x, acc[1][0]);
            acc[1][1] = fmaf(a.y, b.y, acc[1][1]);
            acc[1][2] = fmaf(a.y, b.z, acc[1][2]);
            acc[1][3] = fmaf(a.y, b.w, acc[1][3]);
            acc[2][0] = fmaf(a.z, b.x, acc[2][0]);
            acc[2][1] = fmaf(a.z, b.y, acc[2][1]);
            acc[2][2] = fmaf(a.z, b.z, acc[2][2]);
            acc[2][3] = fmaf(a.z, b.w, acc[2][3]);
            acc[3][0] = fmaf(a.w, b.x, acc[3][0]);
            acc[3][1] = fmaf(a.w, b.y, acc[3][1]);
            acc[3][2] = fmaf(a.w, b.z, acc[3][2]);
            acc[3][3] = fmaf(a.w, b.w, acc[3][3]);
        }
        __syncthreads();
    }
#pragma unroll
    for (int i = 0; i < 4; ++i) {
        float* Cp = C + (size_t)(m0 + (ty << 2) + i) * ldc + n0 + (tx << 2);
        if (accum) {
            Cp[0] += acc[i][0]; Cp[1] += acc[i][1]; Cp[2] += acc[i][2]; Cp[3] += acc[i][3];
        } else {
            Cp[0] = acc[i][0]; Cp[1] = acc[i][1]; Cp[2] = acc[i][2]; Cp[3] = acc[i][3];
        }
    }
}

// ---------------- skinny GEMM for x_proj: [L,1024] @ [1024,64] -> [L,64] --------
// block = 256 threads = 4 rows x 64 cols; K hardcoded 1024, N=ldc=64.
__global__ __launch_bounds__(256) void gemm_rows4(
    const float* __restrict__ A, int lda,
    const float* __restrict__ B, float* __restrict__ C)
{
    __shared__ float rows[4 * 1024];
    const int tid = threadIdx.x;
    const int t0 = blockIdx.x << 2;
    for (int i = tid; i < 4 * 1024; i += 256)
        rows[i] = A[(size_t)(t0 + (i >> 10)) * lda + (i & 1023)];
    __syncthreads();
    const int row = tid >> 6, col = tid & 63;
    const float* rp = &rows[row << 10];
    float acc = 0.f;
#pragma unroll 4
    for (int k = 0; k < 1024; ++k)
        acc = fmaf(rp[k], B[k * 64 + col], acc);
    C[(size_t)(t0 + row) * 64 + col] = acc;
}

// ---------------- fc1 epilogue: gelu(tmp + b) + coords@Wpos + bpos --------------
__global__ __launch_bounds__(256) void fc1_epi(
    const float* __restrict__ tmp, const float* __restrict__ bfc1,
    const float* __restrict__ coords, const float* __restrict__ Wpos,
    const float* __restrict__ bpos, float* __restrict__ h)
{
    int idx = blockIdx.x * 256 + threadIdx.x;   // L*DM
    int t = idx >> 9, j = idx & 511;
    float v = tmp[idx] + bfc1[j];
    float g = 0.5f * v * (1.f + erff(v * 0.70710678118654752f));
    h[idx] = g + coords[2 * t] * Wpos[j] + coords[2 * t + 1] * Wpos[DM + j] + bpos[j];
}

// ---------------- RMSNorm over last dim (512) -----------------------------------
__global__ __launch_bounds__(256) void rmsnorm_k(
    const float* __restrict__ h, const float* __restrict__ w, float* __restrict__ out)
{
    const int t = blockIdx.x, tid = threadIdx.x;
    float a = h[(size_t)t * DM + tid];
    float b = h[(size_t)t * DM + 256 + tid];
    float ss = a * a + b * b;
#pragma unroll
    for (int off = 1; off < 64; off <<= 1) ss += __shfl_xor(ss, off);
    __shared__ float red[4];
    if ((tid & 63) == 0) red[tid >> 6] = ss;
    __syncthreads();
    float tot = red[0] + red[1] + red[2] + red[3];
    float inv = rsqrtf(tot * (1.f / DM) + 1e-5f);
    out[(size_t)t * DM + tid] = a * inv * w[tid];
    out[(size_t)t * DM + 256 + tid] = b * inv * w[256 + tid];
}

// ---------------- LayerNorm over last dim (512) ---------------------------------
__global__ __launch_bounds__(256) void layernorm_k(
    const float* __restrict__ h, const float* __restrict__ w,
    const float* __restrict__ bb, float* __restrict__ out)
{
    const int t = blockIdx.x, tid = threadIdx.x;
    float a = h[(size_t)t * DM + tid];
    float b = h[(size_t)t * DM + 256 + tid];
    float s = a + b;
#pragma unroll
    for (int off = 1; off < 64; off <<= 1) s += __shfl_xor(s, off);
    __shared__ float red1[4];
    if ((tid & 63) == 0) red1[tid >> 6] = s;
    __syncthreads();
    float mean = (red1[0] + red1[1] + red1[2] + red1[3]) * (1.f / DM);
    float da = a - mean, db = b - mean;
    float vs = da * da + db * db;
#pragma unroll
    for (int off = 1; off < 64; off <<= 1) vs += __shfl_xor(vs, off);
    __shared__ float red2[4];
    if ((tid & 63) == 0) red2[tid >> 6] = vs;
    __syncthreads();
    float var = (red2[0] + red2[1] + red2[2] + red2[3]) * (1.f / DM);
    float inv = rsqrtf(var + 1e-5f);
    out[(size_t)t * DM + tid] = da * inv * w[tid] + bb[tid];
    out[(size_t)t * DM + 256 + tid] = db * inv * w[256 + tid] + bb[256 + tid];
}

// ---------------- causal depthwise conv (k=4) + SiLU ----------------------------
// input xi is the first DI columns of xz (ld = 2*DI)
__global__ __launch_bounds__(256) void conv_silu_k(
    const float* __restrict__ xz, const float* __restrict__ cw,
    const float* __restrict__ cb, float* __restrict__ xc)
{
    int idx = blockIdx.x * 256 + threadIdx.x;   // L*DI
    int t = idx >> 10, c = idx & 1023;
    float w0 = cw[c * 4], w1 = cw[c * 4 + 1], w2 = cw[c * 4 + 2], w3 = cw[c * 4 + 3];
    float s = cb[c];
    if (t >= 3) s = fmaf(xz[(size_t)(t - 3) * 2048 + c], w0, s);
    if (t >= 2) s = fmaf(xz[(size_t)(t - 2) * 2048 + c], w1, s);
    if (t >= 1) s = fmaf(xz[(size_t)(t - 1) * 2048 + c], w2, s);
    s = fmaf(xz[(size_t)t * 2048 + c], w3, s);
    xc[idx] = siluf(s);
}

// ---------------- softplus(delta + dtb) in place --------------------------------
__global__ __launch_bounds__(256) void softplus_k(
    float* __restrict__ delta, const float* __restrict__ dtb)
{
    int idx = blockIdx.x * 256 + threadIdx.x;   // L*DI
    int d = idx & 1023;
    float v = delta[idx] + dtb[d];
    delta[idx] = fmaxf(v, 0.f) + log1pf(expf(-fabsf(v)));
}

// ---------------- selective scan + C-proj + D skip + z gate ---------------------
// thread = (d, n): 16 channels x 16 states per block, 64 blocks.
__global__ __launch_bounds__(256) void scan_k(
    const float* __restrict__ delta, const float* __restrict__ xc,
    const float* __restrict__ dbc, const float* __restrict__ xz,
    const float* __restrict__ alog, const float* __restrict__ Dp,
    float* __restrict__ y)
{
    __shared__ float sD[64][16], sX[64][16], sB[64][16], sC[64][16], sZ[64][16];
    const int tid = threadIdx.x;
    const int g = tid >> 4, n = tid & 15;
    const int d0 = blockIdx.x << 4;
    const int d = d0 + g;
    const float An = -expf(alog[d * NST + n]);
    const float Dd = Dp[d];
    float h = 0.f;
    for (int t0 = 0; t0 < LSEQ; t0 += 64) {
        __syncthreads();
        for (int i = tid; i < 1024; i += 256) {
            int r = i >> 4, c = i & 15;
            sD[r][c] = delta[(size_t)(t0 + r) * DI + d0 + c];
            sX[r][c] = xc[(size_t)(t0 + r) * DI + d0 + c];
            sB[r][c] = dbc[(size_t)(t0 + r) * 64 + 32 + c];
            sC[r][c] = dbc[(size_t)(t0 + r) * 64 + 48 + c];
            sZ[r][c] = xz[(size_t)(t0 + r) * 2048 + 1024 + d0 + c];
        }
        __syncthreads();
        for (int i = 0; i < 64; ++i) {
            float dl = sD[i][g], xv = sX[i][g];
            float da = expf(dl * An);
            h = fmaf(da, h, dl * xv * sB[i][n]);
            float p = h * sC[i][n];
            p += __shfl_xor(p, 1, 16);
            p += __shfl_xor(p, 2, 16);
            p += __shfl_xor(p, 4, 16);
            p += __shfl_xor(p, 8, 16);
            if (n == 0) {
                float yv = p + xv * Dd;
                float zz = sZ[i][g];
                y[(size_t)(t0 + i) * DI + d] = yv * siluf(zz);
            }
        }
    }
}

// ---------------- attention score: tanh(h@Wa1+ba1)@Wa2+ba2 ----------------------
__global__ __launch_bounds__(128) void attn_score_k(
    const float* __restrict__ hf, const float* __restrict__ Wa1,
    const float* __restrict__ ba1, const float* __restrict__ Wa2,
    const float* __restrict__ ba2, float* __restrict__ scores)
{
    __shared__ float row[DM];
    const int t = blockIdx.x, tid = threadIdx.x;
    for (int i = tid; i < DM; i += 128) row[i] = hf[(size_t)t * DM + i];
    __syncthreads();
    float acc = ba1[tid];
#pragma unroll 4
    for (int i = 0; i < DM; ++i) acc = fmaf(row[i], Wa1[i * 128 + tid], acc);
    float v = tanhf(acc) * Wa2[tid];
#pragma unroll
    for (int off = 1; off < 64; off <<= 1) v += __shfl_xor(v, off);
    __shared__ float red[2];
    if ((tid & 63) == 0) red[tid >> 6] = v;
    __syncthreads();
    if (tid == 0) scores[t] = red[0] + red[1] + ba2[0];
}

// ---------------- softmax over 2048 scores (one block) --------------------------
__global__ __launch_bounds__(1024) void softmax_k(
    const float* __restrict__ s, float* __restrict__ w)
{
    const int tid = threadIdx.x;
    __shared__ float red[16];
    float m = fmaxf(s[tid], s[tid + 1024]);
#pragma unroll
    for (int off = 1; off < 64; off <<= 1) m = fmaxf(m, __shfl_xor(m, off));
    if ((tid & 63) == 0) red[tid >> 6] = m;
    __syncthreads();
    if (tid < 64) {
        float mm = (tid < 16) ? red[tid] : -1e30f;
#pragma unroll
        for (int off = 1; off < 16; off <<= 1) mm = fmaxf(mm, __shfl_xor(mm, off));
        if (tid == 0) red[0] = mm;
    }
    __syncthreads();
    const float gm = red[0];
    __syncthreads();
    float e0 = expf(s[tid] - gm), e1 = expf(s[tid + 1024] - gm);
    float sum = e0 + e1;
#pragma unroll
    for (int off = 1; off < 64; off <<= 1) sum += __shfl_xor(sum, off);
    __shared__ float red2[16];
    if ((tid & 63) == 0) red2[tid >> 6] = sum;
    __syncthreads();
    if (tid < 64) {
        float ss = (tid < 16) ? red2[tid] : 0.f;
#pragma unroll
        for (int off = 1; off < 16; off <<= 1) ss += __shfl_xor(ss, off);
        if (tid == 0) red2[0] = ss;
    }
    __syncthreads();
    float inv = 1.f / red2[0];
    w[tid] = e0 * inv;
    w[tid + 1024] = e1 * inv;
}

// ---------------- pooled[j] = sum_t w[t]*hf[t,j] --------------------------------
__global__ __launch_bounds__(256) void pooled_k(
    const float* __restrict__ wts, const float* __restrict__ hf, float* __restrict__ pooled)
{
    const int j = blockIdx.x * 256 + threadIdx.x;   // DM total
    float acc = 0.f;
    for (int t = 0; t < LSEQ; ++t) acc = fmaf(wts[t], hf[(size_t)t * DM + j], acc);
    pooled[j] = acc;
}

// ---------------- ConvT 1x1 -> 4x4 (s=1,p=0), 512->256, relu --------------------
__global__ __launch_bounds__(256) void ct1_k(
    const float* __restrict__ feat, const float* __restrict__ w,
    const float* __restrict__ b, float* __restrict__ out)
{
    int idx = blockIdx.x * 256 + threadIdx.x;   // 256*16
    int o = idx >> 4, p = idx & 15;
    float s = b[o];
    for (int ci = 0; ci < 512; ++ci)
        s = fmaf(feat[ci], w[ci * 4096 + (o << 4) + p], s);
    out[idx] = fmaxf(s, 0.f);
}

// ---------------- ConvT 4x4 -> 16x16 (s=4,p=0), 256->128, relu ------------------
__global__ __launch_bounds__(256) void ct2_k(
    const float* __restrict__ in, const float* __restrict__ w,
    const float* __restrict__ b, float* __restrict__ out)
{
    int idx = blockIdx.x * 256 + threadIdx.x;   // 128*16*16
    int o = idx >> 8, rem = idx & 255;
    int yy = rem >> 4, xx = rem & 15;
    int iy = yy >> 2, ix = xx >> 2, ky = yy & 3, kx = xx & 3;
    float s = b[o];
    const float* ip = in + iy * 4 + ix;
    const float* wp = w + (o << 4) + (ky << 2) + kx;
    for (int ci = 0; ci < 256; ++ci)
        s = fmaf(ip[ci * 16], wp[ci * 2048], s);
    out[idx] = fmaxf(s, 0.f);
}

// ---------------- generic ConvT (k=4,s=2,p=1), Hin -> 2*Hin ---------------------
__global__ __launch_bounds__(256) void ctup_k(
    const float* __restrict__ in, const float* __restrict__ w,
    const float* __restrict__ b, float* __restrict__ out,
    int Cin, int Cout, int Hin, int relu)
{
    const int Hout = Hin * 2;
    int idx = blockIdx.x * 256 + threadIdx.x;
    int total = Cout * Hout * Hout;
    if (idx >= total) return;
    int o = idx / (Hout * Hout);
    int rem = idx - o * (Hout * Hout);
    int yy = rem / Hout, xx = rem - (rem / Hout) * Hout;
    float s = b[o];
    for (int ky = 0; ky < 4; ++ky) {
        int ty = yy + 1 - ky;
        if (ty & 1) continue;
        int iy = ty >> 1;
        if (iy < 0 || iy >= Hin) continue;
        for (int kx = 0; kx < 4; ++kx) {
            int ux = xx + 1 - kx;
            if (ux & 1) continue;
            int ix = ux >> 1;
            if (ix < 0 || ix >= Hin) continue;
            const float* ip = in + iy * Hin + ix;
            const float* wp = w + o * 16 + ky * 4 + kx;
            float acc = 0.f;
            for (int ci = 0; ci < Cin; ++ci)
                acc = fmaf(ip[(size_t)ci * Hin * Hin], wp[(size_t)ci * Cout * 16], acc);
            s += acc;
        }
    }
    out[idx] = relu ? fmaxf(s, 0.f) : s;
}

extern "C" void kernel_launch(void* const* d_in, const int* in_sizes, int n_in,
                              void* d_out, int out_size, void* d_ws, size_t ws_size,
                              hipStream_t stream)
{
    const float* x      = (const float*)d_in[0];
    const float* coords = (const float*)d_in[1];
    const float* Wfc1   = (const float*)d_in[2];
    const float* bfc1   = (const float*)d_in[3];
    const float* Wpos   = (const float*)d_in[4];
    const float* bpos   = (const float*)d_in[5];
    const float* in_w   = (const float*)d_in[6];
    const float* conv_w = (const float*)d_in[7];
    const float* conv_b = (const float*)d_in[8];
    const float* x_w    = (const float*)d_in[9];
    const float* dt_w   = (const float*)d_in[10];
    const float* dt_b   = (const float*)d_in[11];
    const float* A_log  = (const float*)d_in[12];
    const float* Dp     = (const float*)d_in[13];
    const float* out_w  = (const float*)d_in[14];
    const float* rms_w  = (const float*)d_in[15];
    const float* ln_w   = (const float*)d_in[16];
    const float* ln_b   = (const float*)d_in[17];
    const float* Wa1    = (const float*)d_in[18];
    const float* ba1    = (const float*)d_in[19];
    const float* Wa2    = (const float*)d_in[20];
    const float* ba2    = (const float*)d_in[21];
    const float* ct1w   = (const float*)d_in[22];
    const float* ct1b   = (const float*)d_in[23];
    const float* ct2w   = (const float*)d_in[24];
    const float* ct2b   = (const float*)d_in[25];
    const float* ct3w   = (const float*)d_in[26];
    const float* ct3b   = (const float*)d_in[27];
    const float* ct4w   = (const float*)d_in[28];
    const float* ct4b   = (const float*)d_in[29];
    const float* ct5w   = (const float*)d_in[30];
    const float* ct5b   = (const float*)d_in[31];

    // workspace layout (floats); total ~14.0M floats = ~54 MB
    float* ws     = (float*)d_ws;
    float* h      = ws;                         // L*DM
    float* hn     = h + (size_t)LSEQ * DM;      // L*DM (also fc1 temp)
    float* xz     = hn + (size_t)LSEQ * DM;     // L*2048
    float* xc     = xz + (size_t)LSEQ * 2 * DI; // L*DI
    float* dbc    = xc + (size_t)LSEQ * DI;     // L*64
    float* delta  = dbc + (size_t)LSEQ * 64;    // L*DI
    float* yb     = delta + (size_t)LSEQ * DI;  // L*DI
    float* hf     = yb + (size_t)LSEQ * DI;     // L*DM
    float* scores = hf + (size_t)LSEQ * DM;     // L
    float* wts    = scores + LSEQ;              // L
    float* pooled = wts + LSEQ;                 // DM
    float* c1     = pooled + DM;                // 256*16
    float* c2     = c1 + 256 * 16;              // 128*256
    float* c3     = c2 + 128 * 256;             // 64*1024
    float* c4     = c3 + 64 * 1024;             // 32*4096

    // fc1 + gelu + pos-emb
    gemm64<<<dim3(DM / 64, LSEQ / 64), 256, 0, stream>>>(x, 1024, Wfc1, DM, hn, DM, 1024, 0);
    fc1_epi<<<LSEQ * DM / 256, 256, 0, stream>>>(hn, bfc1, coords, Wpos, bpos, h);

    for (int l = 0; l < 2; ++l) {
        rmsnorm_k<<<LSEQ, 256, 0, stream>>>(h, rms_w + l * DM, hn);
        gemm64<<<dim3(2 * DI / 64, LSEQ / 64), 256, 0, stream>>>(
            hn, DM, in_w + (size_t)l * DM * 2 * DI, 2 * DI, xz, 2 * DI, DM, 0);
        conv_silu_k<<<LSEQ * DI / 256, 256, 0, stream>>>(
            xz, conv_w + (size_t)l * DI * 4, conv_b + (size_t)l * DI, xc);
        gemm_rows4<<<LSEQ / 4, 256, 0, stream>>>(xc, DI, x_w + (size_t)l * DI * 64, dbc);
        gemm64<<<dim3(DI / 64, LSEQ / 64), 256, 0, stream>>>(
            dbc, 64, dt_w + (size_t)l * 32 * DI, DI, delta, DI, 32, 0);
        softplus_k<<<LSEQ * DI / 256, 256, 0, stream>>>(delta, dt_b + (size_t)l * DI);
        scan_k<<<DI / 16, 256, 0, stream>>>(
            delta, xc, dbc, xz, A_log + (size_t)l * DI * NST, Dp + (size_t)l * DI, yb);
        gemm64<<<dim3(DM / 64, LSEQ / 64), 256, 0, stream>>>(
            yb, DI, out_w + (size_t)l * DI * DM, DM, h, DM, DI, 1);
    }

    layernorm_k<<<LSEQ, 256, 0, stream>>>(h, ln_w, ln_b, hf);
    attn_score_k<<<LSEQ, 128, 0, stream>>>(hf, Wa1, ba1, Wa2, ba2, scores);
    softmax_k<<<1, 1024, 0, stream>>>(scores, wts);
    pooled_k<<<DM / 256, 256, 0, stream>>>(wts, hf, pooled);

    ct1_k<<<16, 256, 0, stream>>>(pooled, ct1w, ct1b, c1);
    ct2_k<<<128, 256, 0, stream>>>(c1, ct2w, ct2b, c2);
    ctup_k<<<256, 256, 0, stream>>>(c2, ct3w, ct3b, c3, 128, 64, 16, 1);
    ctup_k<<<512, 256, 0, stream>>>(c3, ct4w, ct4b, c4, 64, 32, 32, 1);
    ctup_k<<<704, 256, 0, stream>>>(c4, ct5w, ct5b, (float*)d_out, 32, 11, 64, 0);
}

// Round 2
// 1332.049 us; speedup vs baseline: 1.8680x; 1.8680x over previous
//
#include <hip/hip_runtime.h>
#include <math.h>

#define LSEQ 2048
#define DM 512
#define DI 1024
#define NST 16
#define CHUNK 128
#define NC (LSEQ / CHUNK)

__device__ __forceinline__ float siluf(float v) { return v / (1.f + expf(-v)); }

// ---------------- generic fp32 GEMM: C[M,N] = A[M,K] @ B[K,N] (+C if accum) -----
__global__ __launch_bounds__(256) void gemm64(
    const float* __restrict__ A, int lda,
    const float* __restrict__ B, int ldb,
    float* __restrict__ C, int ldc,
    int K, int accum)
{
    __shared__ float As[16][68];
    __shared__ float Bs[16][68];
    const int tid = threadIdx.x;
    const int tx = tid & 15, ty = tid >> 4;
    const int m0 = blockIdx.y << 6, n0 = blockIdx.x << 6;
    const int arow = tid >> 2, akk = (tid & 3) << 2;
    const int bkr = tid >> 4, bnn = (tid & 15) << 2;
    const float* Ap = A + (size_t)(m0 + arow) * lda + akk;
    const float* Bp = B + (size_t)bkr * ldb + n0 + bnn;
    float acc[4][4] = {};
    for (int k0 = 0; k0 < K; k0 += 16) {
        float4 av = *(const float4*)(Ap + k0);
        float4 bv = *(const float4*)(Bp + (size_t)k0 * ldb);
        As[akk + 0][arow] = av.x;
        As[akk + 1][arow] = av.y;
        As[akk + 2][arow] = av.z;
        As[akk + 3][arow] = av.w;
        *(float4*)&Bs[bkr][bnn] = bv;
        __syncthreads();
#pragma unroll
        for (int kk = 0; kk < 16; ++kk) {
            float4 a = *(const float4*)&As[kk][ty << 2];
            float4 b = *(const float4*)&Bs[kk][tx << 2];
            acc[0][0] = fmaf(a.x, b.x, acc[0][0]);
            acc[0][1] = fmaf(a.x, b.y, acc[0][1]);
            acc[0][2] = fmaf(a.x, b.z, acc[0][2]);
            acc[0][3] = fmaf(a.x, b.w, acc[0][3]);
            acc[1][0] = fmaf(a.y, b.x, acc[1][0]);
            acc[1][1] = fmaf(a.y, b.y, acc[1][1]);
            acc[1][2] = fmaf(a.y, b.z, acc[1][2]);
            acc[1][3] = fmaf(a.y, b.w, acc[1][3]);
            acc[2][0] = fmaf(a.z, b.x, acc[2][0]);
            acc[2][1] = fmaf(a.z, b.y, acc[2][1]);
            acc[2][2] = fmaf(a.z, b.z, acc[2][2]);
            acc[2][3] = fmaf(a.z, b.w, acc[2][3]);
            acc[3][0] = fmaf(a.w, b.x, acc[3][0]);
            acc[3][1] = fmaf(a.w, b.y, acc[3][1]);
            acc[3][2] = fmaf(a.w, b.z, acc[3][2]);
            acc[3][3] = fmaf(a.w, b.w, acc[3][3]);
        }
        __syncthreads();
    }
#pragma unroll
    for (int i = 0; i < 4; ++i) {
        float* Cp = C + (size_t)(m0 + (ty << 2) + i) * ldc + n0 + (tx << 2);
        if (accum) {
            Cp[0] += acc[i][0]; Cp[1] += acc[i][1]; Cp[2] += acc[i][2]; Cp[3] += acc[i][3];
        } else {
            Cp[0] = acc[i][0]; Cp[1] = acc[i][1]; Cp[2] = acc[i][2]; Cp[3] = acc[i][3];
        }
    }
}

// ---------------- skinny GEMM for x_proj: [L,1024] @ [1024,64] -> [L,64] --------
__global__ __launch_bounds__(256) void gemm_rows4(
    const float* __restrict__ A, int lda,
    const float* __restrict__ B, float* __restrict__ C)
{
    __shared__ float rows[4 * 1024];
    const int tid = threadIdx.x;
    const int t0 = blockIdx.x << 2;
    for (int i = tid; i < 4 * 1024; i += 256)
        rows[i] = A[(size_t)(t0 + (i >> 10)) * lda + (i & 1023)];
    __syncthreads();
    const int row = tid >> 6, col = tid & 63;
    const float* rp = &rows[row << 10];
    float acc = 0.f;
#pragma unroll 4
    for (int k = 0; k < 1024; ++k)
        acc = fmaf(rp[k], B[k * 64 + col], acc);
    C[(size_t)(t0 + row) * 64 + col] = acc;
}

// ---------------- fc1 epilogue: gelu(tmp + b) + coords@Wpos + bpos --------------
__global__ __launch_bounds__(256) void fc1_epi(
    const float* __restrict__ tmp, const float* __restrict__ bfc1,
    const float* __restrict__ coords, const float* __restrict__ Wpos,
    const float* __restrict__ bpos, float* __restrict__ h)
{
    int idx = blockIdx.x * 256 + threadIdx.x;   // L*DM
    int t = idx >> 9, j = idx & 511;
    float v = tmp[idx] + bfc1[j];
    float g = 0.5f * v * (1.f + erff(v * 0.70710678118654752f));
    h[idx] = g + coords[2 * t] * Wpos[j] + coords[2 * t + 1] * Wpos[DM + j] + bpos[j];
}

// ---------------- RMSNorm over last dim (512) -----------------------------------
__global__ __launch_bounds__(256) void rmsnorm_k(
    const float* __restrict__ h, const float* __restrict__ w, float* __restrict__ out)
{
    const int t = blockIdx.x, tid = threadIdx.x;
    float a = h[(size_t)t * DM + tid];
    float b = h[(size_t)t * DM + 256 + tid];
    float ss = a * a + b * b;
#pragma unroll
    for (int off = 1; off < 64; off <<= 1) ss += __shfl_xor(ss, off);
    __shared__ float red[4];
    if ((tid & 63) == 0) red[tid >> 6] = ss;
    __syncthreads();
    float tot = red[0] + red[1] + red[2] + red[3];
    float inv = rsqrtf(tot * (1.f / DM) + 1e-5f);
    out[(size_t)t * DM + tid] = a * inv * w[tid];
    out[(size_t)t * DM + 256 + tid] = b * inv * w[256 + tid];
}

// ---------------- LayerNorm over last dim (512) ---------------------------------
__global__ __launch_bounds__(256) void layernorm_k(
    const float* __restrict__ h, const float* __restrict__ w,
    const float* __restrict__ bb, float* __restrict__ out)
{
    const int t = blockIdx.x, tid = threadIdx.x;
    float a = h[(size_t)t * DM + tid];
    float b = h[(size_t)t * DM + 256 + tid];
    float s = a + b;
#pragma unroll
    for (int off = 1; off < 64; off <<= 1) s += __shfl_xor(s, off);
    __shared__ float red1[4];
    if ((tid & 63) == 0) red1[tid >> 6] = s;
    __syncthreads();
    float mean = (red1[0] + red1[1] + red1[2] + red1[3]) * (1.f / DM);
    float da = a - mean, db = b - mean;
    float vs = da * da + db * db;
#pragma unroll
    for (int off = 1; off < 64; off <<= 1) vs += __shfl_xor(vs, off);
    __shared__ float red2[4];
    if ((tid & 63) == 0) red2[tid >> 6] = vs;
    __syncthreads();
    float var = (red2[0] + red2[1] + red2[2] + red2[3]) * (1.f / DM);
    float inv = rsqrtf(var + 1e-5f);
    out[(size_t)t * DM + tid] = da * inv * w[tid] + bb[tid];
    out[(size_t)t * DM + 256 + tid] = db * inv * w[256 + tid] + bb[256 + tid];
}

// ---------------- causal depthwise conv (k=4) + SiLU ----------------------------
__global__ __launch_bounds__(256) void conv_silu_k(
    const float* __restrict__ xz, const float* __restrict__ cw,
    const float* __restrict__ cb, float* __restrict__ xc)
{
    int idx = blockIdx.x * 256 + threadIdx.x;   // L*DI
    int t = idx >> 10, c = idx & 1023;
    float w0 = cw[c * 4], w1 = cw[c * 4 + 1], w2 = cw[c * 4 + 2], w3 = cw[c * 4 + 3];
    float s = cb[c];
    if (t >= 3) s = fmaf(xz[(size_t)(t - 3) * 2048 + c], w0, s);
    if (t >= 2) s = fmaf(xz[(size_t)(t - 2) * 2048 + c], w1, s);
    if (t >= 1) s = fmaf(xz[(size_t)(t - 1) * 2048 + c], w2, s);
    s = fmaf(xz[(size_t)t * 2048 + c], w3, s);
    xc[idx] = siluf(s);
}

// ---------------- softplus(delta + dtb) in place --------------------------------
__global__ __launch_bounds__(256) void softplus_k(
    float* __restrict__ delta, const float* __restrict__ dtb)
{
    int idx = blockIdx.x * 256 + threadIdx.x;   // L*DI
    int d = idx & 1023;
    float v = delta[idx] + dtb[d];
    delta[idx] = fmaxf(v, 0.f) + log1pf(expf(-fabsf(v)));
}

// ===================== chunked parallel selective scan ==========================
// Phase 1: per (d-group, chunk) block: local scan with h0=0, emit summaries
//   aprod[c,d,n] = prod_{t in chunk} dA_t    hfin[c,d,n] = local h at chunk end
__global__ __launch_bounds__(256) void scan_p1(
    const float* __restrict__ delta, const float* __restrict__ xc,
    const float* __restrict__ dbc, const float* __restrict__ alog,
    float* __restrict__ aprod, float* __restrict__ hfin)
{
    __shared__ float sD[CHUNK][16], sX[CHUNK][16], sB[CHUNK][16];
    const int tid = threadIdx.x;
    const int g = tid >> 4, n = tid & 15;
    const int d0 = blockIdx.x << 4;
    const int c = blockIdx.y;
    const int t0 = c * CHUNK;
    const int d = d0 + g;
    const float An = -expf(alog[d * NST + n]);
    for (int i = tid; i < CHUNK * 16; i += 256) {
        int r = i >> 4, cc = i & 15;
        sD[r][cc] = delta[(size_t)(t0 + r) * DI + d0 + cc];
        sX[r][cc] = xc[(size_t)(t0 + r) * DI + d0 + cc];
        sB[r][cc] = dbc[(size_t)(t0 + r) * 64 + 32 + cc];
    }
    __syncthreads();
    float h = 0.f, ap = 1.f;
    for (int i = 0; i < CHUNK; ++i) {
        float dl = sD[i][g], xv = sX[i][g];
        float a = expf(dl * An);
        h = fmaf(a, h, dl * xv * sB[i][n]);
        ap *= a;
    }
    size_t idx = ((size_t)c * DI + d) * NST + n;
    aprod[idx] = ap;
    hfin[idx] = h;
}

// Phase 2: serial scan over the NC chunk summaries -> carry-in per chunk
__global__ __launch_bounds__(256) void scan_carry(
    const float* __restrict__ aprod, const float* __restrict__ hfin,
    float* __restrict__ carry)
{
    const int dn = blockIdx.x * 256 + threadIdx.x;   // DI*NST
    float h = 0.f;
    carry[dn] = 0.f;
#pragma unroll
    for (int c = 0; c < NC - 1; ++c) {
        h = fmaf(aprod[(size_t)c * DI * NST + dn], h, hfin[(size_t)c * DI * NST + dn]);
        carry[(size_t)(c + 1) * DI * NST + dn] = h;
    }
}

// Phase 3: re-run chunk scan with carry-in, compute y = (h.C) + x*D, gate silu(z)
__global__ __launch_bounds__(256) void scan_p2(
    const float* __restrict__ delta, const float* __restrict__ xc,
    const float* __restrict__ dbc, const float* __restrict__ xz,
    const float* __restrict__ alog, const float* __restrict__ Dp,
    const float* __restrict__ carry, float* __restrict__ y)
{
    __shared__ float sD[CHUNK][16], sX[CHUNK][16], sB[CHUNK][16], sC[CHUNK][16], sZ[CHUNK][16];
    const int tid = threadIdx.x;
    const int g = tid >> 4, n = tid & 15;
    const int d0 = blockIdx.x << 4;
    const int c = blockIdx.y;
    const int t0 = c * CHUNK;
    const int d = d0 + g;
    const float An = -expf(alog[d * NST + n]);
    const float Dd = Dp[d];
    for (int i = tid; i < CHUNK * 16; i += 256) {
        int r = i >> 4, cc = i & 15;
        sD[r][cc] = delta[(size_t)(t0 + r) * DI + d0 + cc];
        sX[r][cc] = xc[(size_t)(t0 + r) * DI + d0 + cc];
        sB[r][cc] = dbc[(size_t)(t0 + r) * 64 + 32 + cc];
        sC[r][cc] = dbc[(size_t)(t0 + r) * 64 + 48 + cc];
        sZ[r][cc] = xz[(size_t)(t0 + r) * 2048 + 1024 + d0 + cc];
    }
    __syncthreads();
    float h = carry[((size_t)c * DI + d) * NST + n];
    for (int i = 0; i < CHUNK; ++i) {
        float dl = sD[i][g], xv = sX[i][g];
        float a = expf(dl * An);
        h = fmaf(a, h, dl * xv * sB[i][n]);
        float p = h * sC[i][n];
        p += __shfl_xor(p, 1, 16);
        p += __shfl_xor(p, 2, 16);
        p += __shfl_xor(p, 4, 16);
        p += __shfl_xor(p, 8, 16);
        if (n == 0) {
            float yv = p + xv * Dd;
            float zz = sZ[i][g];
            y[(size_t)(t0 + i) * DI + d] = yv * siluf(zz);
        }
    }
}

// ---------------- attention score: tanh(h@Wa1+ba1)@Wa2+ba2 ----------------------
__global__ __launch_bounds__(128) void attn_score_k(
    const float* __restrict__ hf, const float* __restrict__ Wa1,
    const float* __restrict__ ba1, const float* __restrict__ Wa2,
    const float* __restrict__ ba2, float* __restrict__ scores)
{
    __shared__ float row[DM];
    const int t = blockIdx.x, tid = threadIdx.x;
    for (int i = tid; i < DM; i += 128) row[i] = hf[(size_t)t * DM + i];
    __syncthreads();
    float acc = ba1[tid];
#pragma unroll 4
    for (int i = 0; i < DM; ++i) acc = fmaf(row[i], Wa1[i * 128 + tid], acc);
    float v = tanhf(acc) * Wa2[tid];
#pragma unroll
    for (int off = 1; off < 64; off <<= 1) v += __shfl_xor(v, off);
    __shared__ float red[2];
    if ((tid & 63) == 0) red[tid >> 6] = v;
    __syncthreads();
    if (tid == 0) scores[t] = red[0] + red[1] + ba2[0];
}

// ---------------- softmax over 2048 scores (one block) --------------------------
__global__ __launch_bounds__(1024) void softmax_k(
    const float* __restrict__ s, float* __restrict__ w)
{
    const int tid = threadIdx.x;
    __shared__ float red[16];
    float m = fmaxf(s[tid], s[tid + 1024]);
#pragma unroll
    for (int off = 1; off < 64; off <<= 1) m = fmaxf(m, __shfl_xor(m, off));
    if ((tid & 63) == 0) red[tid >> 6] = m;
    __syncthreads();
    if (tid < 64) {
        float mm = (tid < 16) ? red[tid] : -1e30f;
#pragma unroll
        for (int off = 1; off < 16; off <<= 1) mm = fmaxf(mm, __shfl_xor(mm, off));
        if (tid == 0) red[0] = mm;
    }
    __syncthreads();
    const float gm = red[0];
    __syncthreads();
    float e0 = expf(s[tid] - gm), e1 = expf(s[tid + 1024] - gm);
    float sum = e0 + e1;
#pragma unroll
    for (int off = 1; off < 64; off <<= 1) sum += __shfl_xor(sum, off);
    __shared__ float red2[16];
    if ((tid & 63) == 0) red2[tid >> 6] = sum;
    __syncthreads();
    if (tid < 64) {
        float ss = (tid < 16) ? red2[tid] : 0.f;
#pragma unroll
        for (int off = 1; off < 16; off <<= 1) ss += __shfl_xor(ss, off);
        if (tid == 0) red2[0] = ss;
    }
    __syncthreads();
    float inv = 1.f / red2[0];
    w[tid] = e0 * inv;
    w[tid + 1024] = e1 * inv;
}

// ---------------- pooled[j] = sum_t w[t]*hf[t,j] --------------------------------
__global__ __launch_bounds__(256) void pooled_k(
    const float* __restrict__ wts, const float* __restrict__ hf, float* __restrict__ pooled)
{
    const int j = blockIdx.x * 256 + threadIdx.x;   // DM total
    float acc = 0.f;
    for (int t = 0; t < LSEQ; ++t) acc = fmaf(wts[t], hf[(size_t)t * DM + j], acc);
    pooled[j] = acc;
}

// ---------------- ConvT 1x1 -> 4x4 (s=1,p=0), 512->256, relu --------------------
__global__ __launch_bounds__(256) void ct1_k(
    const float* __restrict__ feat, const float* __restrict__ w,
    const float* __restrict__ b, float* __restrict__ out)
{
    int idx = blockIdx.x * 256 + threadIdx.x;   // 256*16
    int o = idx >> 4, p = idx & 15;
    float s = b[o];
    for (int ci = 0; ci < 512; ++ci)
        s = fmaf(feat[ci], w[ci * 4096 + (o << 4) + p], s);
    out[idx] = fmaxf(s, 0.f);
}

// ---------------- ConvT 4x4 -> 16x16 (s=4,p=0), 256->128, relu ------------------
__global__ __launch_bounds__(256) void ct2_k(
    const float* __restrict__ in, const float* __restrict__ w,
    const float* __restrict__ b, float* __restrict__ out)
{
    int idx = blockIdx.x * 256 + threadIdx.x;   // 128*16*16
    int o = idx >> 8, rem = idx & 255;
    int yy = rem >> 4, xx = rem & 15;
    int iy = yy >> 2, ix = xx >> 2, ky = yy & 3, kx = xx & 3;
    float s = b[o];
    const float* ip = in + iy * 4 + ix;
    const float* wp = w + (o << 4) + (ky << 2) + kx;
    for (int ci = 0; ci < 256; ++ci)
        s = fmaf(ip[ci * 16], wp[ci * 2048], s);
    out[idx] = fmaxf(s, 0.f);
}

// ---------------- generic ConvT (k=4,s=2,p=1), Hin -> 2*Hin ---------------------
__global__ __launch_bounds__(256) void ctup_k(
    const float* __restrict__ in, const float* __restrict__ w,
    const float* __restrict__ b, float* __restrict__ out,
    int Cin, int Cout, int Hin, int relu)
{
    const int Hout = Hin * 2;
    int idx = blockIdx.x * 256 + threadIdx.x;
    int total = Cout * Hout * Hout;
    if (idx >= total) return;
    int o = idx / (Hout * Hout);
    int rem = idx - o * (Hout * Hout);
    int yy = rem / Hout, xx = rem - (rem / Hout) * Hout;
    float s = b[o];
    for (int ky = 0; ky < 4; ++ky) {
        int ty = yy + 1 - ky;
        if (ty & 1) continue;
        int iy = ty >> 1;
        if (iy < 0 || iy >= Hin) continue;
        for (int kx = 0; kx < 4; ++kx) {
            int ux = xx + 1 - kx;
            if (ux & 1) continue;
            int ix = ux >> 1;
            if (ix < 0 || ix >= Hin) continue;
            const float* ip = in + iy * Hin + ix;
            const float* wp = w + o * 16 + ky * 4 + kx;
            float acc = 0.f;
            for (int ci = 0; ci < Cin; ++ci)
                acc = fmaf(ip[(size_t)ci * Hin * Hin], wp[(size_t)ci * Cout * 16], acc);
            s += acc;
        }
    }
    out[idx] = relu ? fmaxf(s, 0.f) : s;
}

extern "C" void kernel_launch(void* const* d_in, const int* in_sizes, int n_in,
                              void* d_out, int out_size, void* d_ws, size_t ws_size,
                              hipStream_t stream)
{
    const float* x      = (const float*)d_in[0];
    const float* coords = (const float*)d_in[1];
    const float* Wfc1   = (const float*)d_in[2];
    const float* bfc1   = (const float*)d_in[3];
    const float* Wpos   = (const float*)d_in[4];
    const float* bpos   = (const float*)d_in[5];
    const float* in_w   = (const float*)d_in[6];
    const float* conv_w = (const float*)d_in[7];
    const float* conv_b = (const float*)d_in[8];
    const float* x_w    = (const float*)d_in[9];
    const float* dt_w   = (const float*)d_in[10];
    const float* dt_b   = (const float*)d_in[11];
    const float* A_log  = (const float*)d_in[12];
    const float* Dp     = (const float*)d_in[13];
    const float* out_w  = (const float*)d_in[14];
    const float* rms_w  = (const float*)d_in[15];
    const float* ln_w   = (const float*)d_in[16];
    const float* ln_b   = (const float*)d_in[17];
    const float* Wa1    = (const float*)d_in[18];
    const float* ba1    = (const float*)d_in[19];
    const float* Wa2    = (const float*)d_in[20];
    const float* ba2    = (const float*)d_in[21];
    const float* ct1w   = (const float*)d_in[22];
    const float* ct1b   = (const float*)d_in[23];
    const float* ct2w   = (const float*)d_in[24];
    const float* ct2b   = (const float*)d_in[25];
    const float* ct3w   = (const float*)d_in[26];
    const float* ct3b   = (const float*)d_in[27];
    const float* ct4w   = (const float*)d_in[28];
    const float* ct4b   = (const float*)d_in[29];
    const float* ct5w   = (const float*)d_in[30];
    const float* ct5b   = (const float*)d_in[31];

    // workspace layout (floats)
    float* ws     = (float*)d_ws;
    float* h      = ws;                         // L*DM
    float* hn     = h + (size_t)LSEQ * DM;      // L*DM (also fc1 temp)
    float* xz     = hn + (size_t)LSEQ * DM;     // L*2048
    float* xc     = xz + (size_t)LSEQ * 2 * DI; // L*DI
    float* dbc    = xc + (size_t)LSEQ * DI;     // L*64
    float* delta  = dbc + (size_t)LSEQ * 64;    // L*DI
    float* yb     = delta + (size_t)LSEQ * DI;  // L*DI
    float* hf     = yb + (size_t)LSEQ * DI;     // L*DM
    float* scores = hf + (size_t)LSEQ * DM;     // L
    float* wts    = scores + LSEQ;              // L
    float* pooled = wts + LSEQ;                 // DM
    float* c1     = pooled + DM;                // 256*16
    float* c2     = c1 + 256 * 16;              // 128*256
    float* c3     = c2 + 128 * 256;             // 64*1024
    float* c4     = c3 + 64 * 1024;             // 32*4096
    float* aprod  = c4 + 32 * 4096;             // NC*DI*NST
    float* hfin   = aprod + (size_t)NC * DI * NST;
    float* carry  = hfin + (size_t)NC * DI * NST;

    // fc1 + gelu + pos-emb
    gemm64<<<dim3(DM / 64, LSEQ / 64), 256, 0, stream>>>(x, 1024, Wfc1, DM, hn, DM, 1024, 0);
    fc1_epi<<<LSEQ * DM / 256, 256, 0, stream>>>(hn, bfc1, coords, Wpos, bpos, h);

    for (int l = 0; l < 2; ++l) {
        rmsnorm_k<<<LSEQ, 256, 0, stream>>>(h, rms_w + l * DM, hn);
        gemm64<<<dim3(2 * DI / 64, LSEQ / 64), 256, 0, stream>>>(
            hn, DM, in_w + (size_t)l * DM * 2 * DI, 2 * DI, xz, 2 * DI, DM, 0);
        conv_silu_k<<<LSEQ * DI / 256, 256, 0, stream>>>(
            xz, conv_w + (size_t)l * DI * 4, conv_b + (size_t)l * DI, xc);
        gemm_rows4<<<LSEQ / 4, 256, 0, stream>>>(xc, DI, x_w + (size_t)l * DI * 64, dbc);
        gemm64<<<dim3(DI / 64, LSEQ / 64), 256, 0, stream>>>(
            dbc, 64, dt_w + (size_t)l * 32 * DI, DI, delta, DI, 32, 0);
        softplus_k<<<LSEQ * DI / 256, 256, 0, stream>>>(delta, dt_b + (size_t)l * DI);
        scan_p1<<<dim3(DI / 16, NC), 256, 0, stream>>>(
            delta, xc, dbc, A_log + (size_t)l * DI * NST, aprod, hfin);
        scan_carry<<<DI * NST / 256, 256, 0, stream>>>(aprod, hfin, carry);
        scan_p2<<<dim3(DI / 16, NC), 256, 0, stream>>>(
            delta, xc, dbc, xz, A_log + (size_t)l * DI * NST, Dp + (size_t)l * DI,
            carry, yb);
        gemm64<<<dim3(DM / 64, LSEQ / 64), 256, 0, stream>>>(
            yb, DI, out_w + (size_t)l * DI * DM, DM, h, DM, DI, 1);
    }

    layernorm_k<<<LSEQ, 256, 0, stream>>>(h, ln_w, ln_b, hf);
    attn_score_k<<<LSEQ, 128, 0, stream>>>(hf, Wa1, ba1, Wa2, ba2, scores);
    softmax_k<<<1, 1024, 0, stream>>>(scores, wts);
    pooled_k<<<DM / 256, 256, 0, stream>>>(wts, hf, pooled);

    ct1_k<<<16, 256, 0, stream>>>(pooled, ct1w, ct1b, c1);
    ct2_k<<<128, 256, 0, stream>>>(c1, ct2w, ct2b, c2);
    ctup_k<<<256, 256, 0, stream>>>(c2, ct3w, ct3b, c3, 128, 64, 16, 1);
    ctup_k<<<512, 256, 0, stream>>>(c3, ct4w, ct4b, c4, 64, 32, 32, 1);
    ctup_k<<<704, 256, 0, stream>>>(c4, ct5w, ct5b, (float*)d_out, 32, 11, 64, 0);
}

// Round 4
// 866.622 us; speedup vs baseline: 2.8712x; 1.5371x over previous
//
#include <hip/hip_runtime.h>
#include <math.h>

#define LSEQ 2048
#define DM 512
#define DI 1024
#define NST 16
#define CHUNK 128
#define NC (LSEQ / CHUNK)

__device__ __forceinline__ float siluf(float v) { return v / (1.f + expf(-v)); }

// ---------------- generic fp32 GEMM: C[M,N] = A[M,K] @ B[K,N] (+C if accum) -----
__global__ __launch_bounds__(256) void gemm64(
    const float* __restrict__ A, int lda,
    const float* __restrict__ B, int ldb,
    float* __restrict__ C, int ldc,
    int K, int accum)
{
    __shared__ float As[16][68];
    __shared__ float Bs[16][68];
    const int tid = threadIdx.x;
    const int tx = tid & 15, ty = tid >> 4;
    const int m0 = blockIdx.y << 6, n0 = blockIdx.x << 6;
    const int arow = tid >> 2, akk = (tid & 3) << 2;
    const int bkr = tid >> 4, bnn = (tid & 15) << 2;
    const float* Ap = A + (size_t)(m0 + arow) * lda + akk;
    const float* Bp = B + (size_t)bkr * ldb + n0 + bnn;
    float acc[4][4] = {};
    for (int k0 = 0; k0 < K; k0 += 16) {
        float4 av = *(const float4*)(Ap + k0);
        float4 bv = *(const float4*)(Bp + (size_t)k0 * ldb);
        As[akk + 0][arow] = av.x;
        As[akk + 1][arow] = av.y;
        As[akk + 2][arow] = av.z;
        As[akk + 3][arow] = av.w;
        *(float4*)&Bs[bkr][bnn] = bv;
        __syncthreads();
#pragma unroll
        for (int kk = 0; kk < 16; ++kk) {
            float4 a = *(const float4*)&As[kk][ty << 2];
            float4 b = *(const float4*)&Bs[kk][tx << 2];
            acc[0][0] = fmaf(a.x, b.x, acc[0][0]);
            acc[0][1] = fmaf(a.x, b.y, acc[0][1]);
            acc[0][2] = fmaf(a.x, b.z, acc[0][2]);
            acc[0][3] = fmaf(a.x, b.w, acc[0][3]);
            acc[1][0] = fmaf(a.y, b.x, acc[1][0]);
            acc[1][1] = fmaf(a.y, b.y, acc[1][1]);
            acc[1][2] = fmaf(a.y, b.z, acc[1][2]);
            acc[1][3] = fmaf(a.y, b.w, acc[1][3]);
            acc[2][0] = fmaf(a.z, b.x, acc[2][0]);
            acc[2][1] = fmaf(a.z, b.y, acc[2][1]);
            acc[2][2] = fmaf(a.z, b.z, acc[2][2]);
            acc[2][3] = fmaf(a.z, b.w, acc[2][3]);
            acc[3][0] = fmaf(a.w, b.x, acc[3][0]);
            acc[3][1] = fmaf(a.w, b.y, acc[3][1]);
            acc[3][2] = fmaf(a.w, b.z, acc[3][2]);
            acc[3][3] = fmaf(a.w, b.w, acc[3][3]);
        }
        __syncthreads();
    }
#pragma unroll
    for (int i = 0; i < 4; ++i) {
        float* Cp = C + (size_t)(m0 + (ty << 2) + i) * ldc + n0 + (tx << 2);
        if (accum) {
            Cp[0] += acc[i][0]; Cp[1] += acc[i][1]; Cp[2] += acc[i][2]; Cp[3] += acc[i][3];
        } else {
            Cp[0] = acc[i][0]; Cp[1] = acc[i][1]; Cp[2] = acc[i][2]; Cp[3] = acc[i][3];
        }
    }
}

// ---------------- skinny GEMM for x_proj: [L,1024] @ [1024,64] -> [L,64] --------
__global__ __launch_bounds__(256) void gemm_rows4(
    const float* __restrict__ A, int lda,
    const float* __restrict__ B, float* __restrict__ C)
{
    __shared__ float rows[4 * 1024];
    const int tid = threadIdx.x;
    const int t0 = blockIdx.x << 2;
    for (int i = tid; i < 4 * 1024; i += 256)
        rows[i] = A[(size_t)(t0 + (i >> 10)) * lda + (i & 1023)];
    __syncthreads();
    const int row = tid >> 6, col = tid & 63;
    const float* rp = &rows[row << 10];
    float acc = 0.f;
#pragma unroll 4
    for (int k = 0; k < 1024; ++k)
        acc = fmaf(rp[k], B[k * 64 + col], acc);
    C[(size_t)(t0 + row) * 64 + col] = acc;
}

// ---------------- fc1 epilogue: gelu(tmp + b) + coords@Wpos + bpos --------------
__global__ __launch_bounds__(256) void fc1_epi(
    const float* __restrict__ tmp, const float* __restrict__ bfc1,
    const float* __restrict__ coords, const float* __restrict__ Wpos,
    const float* __restrict__ bpos, float* __restrict__ h)
{
    int idx = blockIdx.x * 256 + threadIdx.x;   // L*DM
    int t = idx >> 9, j = idx & 511;
    float v = tmp[idx] + bfc1[j];
    float g = 0.5f * v * (1.f + erff(v * 0.70710678118654752f));
    h[idx] = g + coords[2 * t] * Wpos[j] + coords[2 * t + 1] * Wpos[DM + j] + bpos[j];
}

// ---------------- RMSNorm over last dim (512) -----------------------------------
__global__ __launch_bounds__(256) void rmsnorm_k(
    const float* __restrict__ h, const float* __restrict__ w, float* __restrict__ out)
{
    const int t = blockIdx.x, tid = threadIdx.x;
    float a = h[(size_t)t * DM + tid];
    float b = h[(size_t)t * DM + 256 + tid];
    float ss = a * a + b * b;
#pragma unroll
    for (int off = 1; off < 64; off <<= 1) ss += __shfl_xor(ss, off);
    __shared__ float red[4];
    if ((tid & 63) == 0) red[tid >> 6] = ss;
    __syncthreads();
    float tot = red[0] + red[1] + red[2] + red[3];
    float inv = rsqrtf(tot * (1.f / DM) + 1e-5f);
    out[(size_t)t * DM + tid] = a * inv * w[tid];
    out[(size_t)t * DM + 256 + tid] = b * inv * w[256 + tid];
}

// ---------------- LayerNorm over last dim (512) ---------------------------------
__global__ __launch_bounds__(256) void layernorm_k(
    const float* __restrict__ h, const float* __restrict__ w,
    const float* __restrict__ bb, float* __restrict__ out)
{
    const int t = blockIdx.x, tid = threadIdx.x;
    float a = h[(size_t)t * DM + tid];
    float b = h[(size_t)t * DM + 256 + tid];
    float s = a + b;
#pragma unroll
    for (int off = 1; off < 64; off <<= 1) s += __shfl_xor(s, off);
    __shared__ float red1[4];
    if ((tid & 63) == 0) red1[tid >> 6] = s;
    __syncthreads();
    float mean = (red1[0] + red1[1] + red1[2] + red1[3]) * (1.f / DM);
    float da = a - mean, db = b - mean;
    float vs = da * da + db * db;
#pragma unroll
    for (int off = 1; off < 64; off <<= 1) vs += __shfl_xor(vs, off);
    __shared__ float red2[4];
    if ((tid & 63) == 0) red2[tid >> 6] = vs;
    __syncthreads();
    float var = (red2[0] + red2[1] + red2[2] + red2[3]) * (1.f / DM);
    float inv = rsqrtf(var + 1e-5f);
    out[(size_t)t * DM + tid] = da * inv * w[tid] + bb[tid];
    out[(size_t)t * DM + 256 + tid] = db * inv * w[256 + tid] + bb[256 + tid];
}

// ---------------- causal depthwise conv (k=4) + SiLU ----------------------------
__global__ __launch_bounds__(256) void conv_silu_k(
    const float* __restrict__ xz, const float* __restrict__ cw,
    const float* __restrict__ cb, float* __restrict__ xc)
{
    int idx = blockIdx.x * 256 + threadIdx.x;   // L*DI
    int t = idx >> 10, c = idx & 1023;
    float w0 = cw[c * 4], w1 = cw[c * 4 + 1], w2 = cw[c * 4 + 2], w3 = cw[c * 4 + 3];
    float s = cb[c];
    if (t >= 3) s = fmaf(xz[(size_t)(t - 3) * 2048 + c], w0, s);
    if (t >= 2) s = fmaf(xz[(size_t)(t - 2) * 2048 + c], w1, s);
    if (t >= 1) s = fmaf(xz[(size_t)(t - 1) * 2048 + c], w2, s);
    s = fmaf(xz[(size_t)t * 2048 + c], w3, s);
    xc[idx] = siluf(s);
}

// ---------------- softplus(delta + dtb) in place --------------------------------
__global__ __launch_bounds__(256) void softplus_k(
    float* __restrict__ delta, const float* __restrict__ dtb)
{
    int idx = blockIdx.x * 256 + threadIdx.x;   // L*DI
    int d = idx & 1023;
    float v = delta[idx] + dtb[d];
    delta[idx] = fmaxf(v, 0.f) + log1pf(expf(-fabsf(v)));
}

// ===================== chunked parallel selective scan ==========================
__global__ __launch_bounds__(256) void scan_p1(
    const float* __restrict__ delta, const float* __restrict__ xc,
    const float* __restrict__ dbc, const float* __restrict__ alog,
    float* __restrict__ aprod, float* __restrict__ hfin)
{
    __shared__ float sD[CHUNK][16], sX[CHUNK][16], sB[CHUNK][16];
    const int tid = threadIdx.x;
    const int g = tid >> 4, n = tid & 15;
    const int d0 = blockIdx.x << 4;
    const int c = blockIdx.y;
    const int t0 = c * CHUNK;
    const int d = d0 + g;
    const float An = -expf(alog[d * NST + n]);
    for (int i = tid; i < CHUNK * 16; i += 256) {
        int r = i >> 4, cc = i & 15;
        sD[r][cc] = delta[(size_t)(t0 + r) * DI + d0 + cc];
        sX[r][cc] = xc[(size_t)(t0 + r) * DI + d0 + cc];
        sB[r][cc] = dbc[(size_t)(t0 + r) * 64 + 32 + cc];
    }
    __syncthreads();
    float h = 0.f, ap = 1.f;
    for (int i = 0; i < CHUNK; ++i) {
        float dl = sD[i][g], xv = sX[i][g];
        float a = expf(dl * An);
        h = fmaf(a, h, dl * xv * sB[i][n]);
        ap *= a;
    }
    size_t idx = ((size_t)c * DI + d) * NST + n;
    aprod[idx] = ap;
    hfin[idx] = h;
}

__global__ __launch_bounds__(256) void scan_carry(
    const float* __restrict__ aprod, const float* __restrict__ hfin,
    float* __restrict__ carry)
{
    const int dn = blockIdx.x * 256 + threadIdx.x;   // DI*NST
    float h = 0.f;
    carry[dn] = 0.f;
#pragma unroll
    for (int c = 0; c < NC - 1; ++c) {
        h = fmaf(aprod[(size_t)c * DI * NST + dn], h, hfin[(size_t)c * DI * NST + dn]);
        carry[(size_t)(c + 1) * DI * NST + dn] = h;
    }
}

__global__ __launch_bounds__(256) void scan_p2(
    const float* __restrict__ delta, const float* __restrict__ xc,
    const float* __restrict__ dbc, const float* __restrict__ xz,
    const float* __restrict__ alog, const float* __restrict__ Dp,
    const float* __restrict__ carry, float* __restrict__ y)
{
    __shared__ float sD[CHUNK][16], sX[CHUNK][16], sB[CHUNK][16], sC[CHUNK][16], sZ[CHUNK][16];
    const int tid = threadIdx.x;
    const int g = tid >> 4, n = tid & 15;
    const int d0 = blockIdx.x << 4;
    const int c = blockIdx.y;
    const int t0 = c * CHUNK;
    const int d = d0 + g;
    const float An = -expf(alog[d * NST + n]);
    const float Dd = Dp[d];
    for (int i = tid; i < CHUNK * 16; i += 256) {
        int r = i >> 4, cc = i & 15;
        sD[r][cc] = delta[(size_t)(t0 + r) * DI + d0 + cc];
        sX[r][cc] = xc[(size_t)(t0 + r) * DI + d0 + cc];
        sB[r][cc] = dbc[(size_t)(t0 + r) * 64 + 32 + cc];
        sC[r][cc] = dbc[(size_t)(t0 + r) * 64 + 48 + cc];
        sZ[r][cc] = xz[(size_t)(t0 + r) * 2048 + 1024 + d0 + cc];
    }
    __syncthreads();
    float h = carry[((size_t)c * DI + d) * NST + n];
    for (int i = 0; i < CHUNK; ++i) {
        float dl = sD[i][g], xv = sX[i][g];
        float a = expf(dl * An);
        h = fmaf(a, h, dl * xv * sB[i][n]);
        float p = h * sC[i][n];
        p += __shfl_xor(p, 1, 16);
        p += __shfl_xor(p, 2, 16);
        p += __shfl_xor(p, 4, 16);
        p += __shfl_xor(p, 8, 16);
        if (n == 0) {
            float yv = p + xv * Dd;
            float zz = sZ[i][g];
            y[(size_t)(t0 + i) * DI + d] = yv * siluf(zz);
        }
    }
}

// ---------------- attention score: tanh(h@Wa1+ba1)@Wa2+ba2 ----------------------
__global__ __launch_bounds__(128) void attn_score_k(
    const float* __restrict__ hf, const float* __restrict__ Wa1,
    const float* __restrict__ ba1, const float* __restrict__ Wa2,
    const float* __restrict__ ba2, float* __restrict__ scores)
{
    __shared__ float row[DM];
    const int t = blockIdx.x, tid = threadIdx.x;
    for (int i = tid; i < DM; i += 128) row[i] = hf[(size_t)t * DM + i];
    __syncthreads();
    float acc = ba1[tid];
#pragma unroll 4
    for (int i = 0; i < DM; ++i) acc = fmaf(row[i], Wa1[i * 128 + tid], acc);
    float v = tanhf(acc) * Wa2[tid];
#pragma unroll
    for (int off = 1; off < 64; off <<= 1) v += __shfl_xor(v, off);
    __shared__ float red[2];
    if ((tid & 63) == 0) red[tid >> 6] = v;
    __syncthreads();
    if (tid == 0) scores[t] = red[0] + red[1] + ba2[0];
}

// ---------------- softmax over 2048 scores (one block) --------------------------
__global__ __launch_bounds__(1024) void softmax_k(
    const float* __restrict__ s, float* __restrict__ w)
{
    const int tid = threadIdx.x;
    __shared__ float red[16];
    float m = fmaxf(s[tid], s[tid + 1024]);
#pragma unroll
    for (int off = 1; off < 64; off <<= 1) m = fmaxf(m, __shfl_xor(m, off));
    if ((tid & 63) == 0) red[tid >> 6] = m;
    __syncthreads();
    if (tid < 64) {
        float mm = (tid < 16) ? red[tid] : -1e30f;
#pragma unroll
        for (int off = 1; off < 16; off <<= 1) mm = fmaxf(mm, __shfl_xor(mm, off));
        if (tid == 0) red[0] = mm;
    }
    __syncthreads();
    const float gm = red[0];
    __syncthreads();
    float e0 = expf(s[tid] - gm), e1 = expf(s[tid + 1024] - gm);
    float sum = e0 + e1;
#pragma unroll
    for (int off = 1; off < 64; off <<= 1) sum += __shfl_xor(sum, off);
    __shared__ float red2[16];
    if ((tid & 63) == 0) red2[tid >> 6] = sum;
    __syncthreads();
    if (tid < 64) {
        float ss = (tid < 16) ? red2[tid] : 0.f;
#pragma unroll
        for (int off = 1; off < 16; off <<= 1) ss += __shfl_xor(ss, off);
        if (tid == 0) red2[0] = ss;
    }
    __syncthreads();
    float inv = 1.f / red2[0];
    w[tid] = e0 * inv;
    w[tid + 1024] = e1 * inv;
}

// ---------------- pooled: two-stage  part[tc,j] then sum ------------------------
__global__ __launch_bounds__(256) void pooled_p1(
    const float* __restrict__ wts, const float* __restrict__ hf, float* __restrict__ part)
{
    const int j = blockIdx.x * 256 + threadIdx.x;   // 0..511
    const int tc = blockIdx.y;                       // 16 chunks of 128
    float acc = 0.f;
    const int t0 = tc * 128;
    for (int t = t0; t < t0 + 128; ++t) acc = fmaf(wts[t], hf[(size_t)t * DM + j], acc);
    part[(size_t)tc * DM + j] = acc;
}

__global__ __launch_bounds__(256) void pooled_p2(
    const float* __restrict__ part, float* __restrict__ pooled)
{
    const int j = blockIdx.x * 256 + threadIdx.x;
    float acc = 0.f;
#pragma unroll
    for (int tc = 0; tc < 16; ++tc) acc += part[(size_t)tc * DM + j];
    pooled[j] = acc;
}

// ---------------- ct1: ConvT 1x1->4x4 (s=1,p=0), 512->256, relu -----------------
// block per out-channel o; threads = 16 pos x 16 ci-groups (32 ci each)
__global__ __launch_bounds__(256) void ct1_fast(
    const float* __restrict__ feat, const float* __restrict__ w,
    const float* __restrict__ b, float* __restrict__ out)
{
    __shared__ float sf[512];
    __shared__ float sRed[256];
    const int o = blockIdx.x, tid = threadIdx.x;
    sf[tid] = feat[tid];
    sf[tid + 256] = feat[tid + 256];
    __syncthreads();
    const int p = tid & 15, g = tid >> 4;
    float acc = 0.f;
#pragma unroll 8
    for (int ci = g * 32; ci < g * 32 + 32; ++ci)
        acc = fmaf(sf[ci], w[ci * 4096 + (o << 4) + p], acc);
    sRed[tid] = acc;
    __syncthreads();
    if (g == 0) {
        float s = b[o];
#pragma unroll
        for (int gg = 0; gg < 16; ++gg) s += sRed[gg * 16 + p];
        out[(o << 4) + p] = fmaxf(s, 0.f);
    }
}

// ---------------- ct2: ConvT 4x4->16x16 (s=4,p=0), 256->128, relu ---------------
// block per (yy, o); threads = 16 xx x 16 ci-groups (16 ci each)
__global__ __launch_bounds__(256) void ct2_fast(
    const float* __restrict__ in, const float* __restrict__ w,
    const float* __restrict__ b, float* __restrict__ out)
{
    __shared__ float sI[1024];   // [ci][ix]
    __shared__ float sW[1024];   // [ci][kx]
    __shared__ float sRed[256];
    const int yy = blockIdx.x, o = blockIdx.y, tid = threadIdx.x;
    const int iy = yy >> 2, ky = yy & 3;
    for (int i = tid; i < 1024; i += 256) {
        int ci = i >> 2, q = i & 3;
        sI[i] = in[(ci << 4) + (iy << 2) + q];
        sW[i] = w[ci * 2048 + (o << 4) + (ky << 2) + q];
    }
    __syncthreads();
    const int xx = tid & 15, g = tid >> 4;
    const int ix = xx >> 2, kx = xx & 3;
    float acc = 0.f;
#pragma unroll 8
    for (int ci = g * 16; ci < g * 16 + 16; ++ci)
        acc = fmaf(sI[(ci << 2) + ix], sW[(ci << 2) + kx], acc);
    sRed[tid] = acc;
    __syncthreads();
    if (g == 0) {
        float s = b[o];
#pragma unroll
        for (int gg = 0; gg < 16; ++gg) s += sRed[gg * 16 + xx];
        out[(o << 8) + (yy << 4) + xx] = fmaxf(s, 0.f);
    }
}

// ---------------- ConvT (k=4,s=2,p=1) Hin->2*Hin, LDS-staged --------------------
// grid (Hout, Cout); 256 threads = Hout columns x (256/Hout) ci-groups (16 ci each).
// Two needed input rows staged in LDS with zero pad columns -> branch-free taps.
__global__ __launch_bounds__(256) void ctup_fast(
    const float* __restrict__ in, const float* __restrict__ w,
    const float* __restrict__ b, float* __restrict__ out,
    int Cin, int Cout, int Hin, int hshift, int relu)
{
    __shared__ float sIn[4608];   // 2 rows x Cin x (Hin+2), max 2*128*18
    __shared__ float sW[2048];    // Cin x 16
    __shared__ float sRed[256];
    const int tid = threadIdx.x;
    const int yy = blockIdx.x, o = blockIdx.y;
    const int Hout = Hin << 1;
    const int ST = Hin + 2;
    const int houtshift = hshift + 1;

    const int ky0 = (yy + 1) & 1;
    const int iy0 = (yy + 1 - ky0) >> 1;
    const int iy1 = iy0 - 1;
    const int row_elems = Cin * ST;

    // zero-fill both padded rows
    for (int i = tid; i < 2 * row_elems; i += 256) sIn[i] = 0.f;
    __syncthreads();
    // load valid input rows (coalesced) and this channel's weights
    const int nload = Cin << hshift;
    if (iy0 < Hin) {
        const float* src = in + ((size_t)iy0 << hshift);
        for (int i = tid; i < nload; i += 256) {
            int ci = i >> hshift, col = i & (Hin - 1);
            sIn[ci * ST + 1 + col] = src[((size_t)ci << (2 * hshift)) + col];
        }
    }
    if (iy1 >= 0) {
        const float* src = in + ((size_t)iy1 << hshift);
        for (int i = tid; i < nload; i += 256) {
            int ci = i >> hshift, col = i & (Hin - 1);
            sIn[row_elems + ci * ST + 1 + col] = src[((size_t)ci << (2 * hshift)) + col];
        }
    }
    for (int i = tid; i < (Cin << 4); i += 256)
        sW[i] = w[(size_t)(i >> 4) * (Cout << 4) + (o << 4) + (i & 15)];
    __syncthreads();

    const int xx = tid & (Hout - 1);
    const int g = tid >> houtshift;
    const int kx0 = (xx + 1) & 1;
    const int ix0 = (xx + 1 - kx0) >> 1;       // slot ix0+1 (0 if padded)
    const int k00 = (ky0 << 2) + kx0;

    float acc = 0.f;
    const float* in1 = sIn + row_elems;
#pragma unroll 4
    for (int ci = g * 16; ci < g * 16 + 16; ++ci) {
        const int base = ci * ST + ix0;
        const float* wr = &sW[ci << 4];
        float i00 = sIn[base + 1], i01 = sIn[base];
        float i10 = in1[base + 1], i11 = in1[base];
        acc = fmaf(i00, wr[k00], acc);
        acc = fmaf(i01, wr[k00 + 2], acc);
        acc = fmaf(i10, wr[k00 + 8], acc);
        acc = fmaf(i11, wr[k00 + 10], acc);
    }
    sRed[tid] = acc;
    __syncthreads();
    if (g == 0) {
        float s = b[o];
        const int XG = 256 >> houtshift;
        for (int gg = 0; gg < XG; ++gg) s += sRed[(gg << houtshift) + xx];
        out[(size_t)o * Hout * Hout + (size_t)yy * Hout + xx] = relu ? fmaxf(s, 0.f) : s;
    }
}

extern "C" void kernel_launch(void* const* d_in, const int* in_sizes, int n_in,
                              void* d_out, int out_size, void* d_ws, size_t ws_size,
                              hipStream_t stream)
{
    const float* x      = (const float*)d_in[0];
    const float* coords = (const float*)d_in[1];
    const float* Wfc1   = (const float*)d_in[2];
    const float* bfc1   = (const float*)d_in[3];
    const float* Wpos   = (const float*)d_in[4];
    const float* bpos   = (const float*)d_in[5];
    const float* in_w   = (const float*)d_in[6];
    const float* conv_w = (const float*)d_in[7];
    const float* conv_b = (const float*)d_in[8];
    const float* x_w    = (const float*)d_in[9];
    const float* dt_w   = (const float*)d_in[10];
    const float* dt_b   = (const float*)d_in[11];
    const float* A_log  = (const float*)d_in[12];
    const float* Dp     = (const float*)d_in[13];
    const float* out_w  = (const float*)d_in[14];
    const float* rms_w  = (const float*)d_in[15];
    const float* ln_w   = (const float*)d_in[16];
    const float* ln_b   = (const float*)d_in[17];
    const float* Wa1    = (const float*)d_in[18];
    const float* ba1    = (const float*)d_in[19];
    const float* Wa2    = (const float*)d_in[20];
    const float* ba2    = (const float*)d_in[21];
    const float* ct1w   = (const float*)d_in[22];
    const float* ct1b   = (const float*)d_in[23];
    const float* ct2w   = (const float*)d_in[24];
    const float* ct2b   = (const float*)d_in[25];
    const float* ct3w   = (const float*)d_in[26];
    const float* ct3b   = (const float*)d_in[27];
    const float* ct4w   = (const float*)d_in[28];
    const float* ct4b   = (const float*)d_in[29];
    const float* ct5w   = (const float*)d_in[30];
    const float* ct5b   = (const float*)d_in[31];

    // workspace layout (floats)
    float* ws     = (float*)d_ws;
    float* h      = ws;                         // L*DM
    float* hn     = h + (size_t)LSEQ * DM;      // L*DM (also fc1 temp)
    float* xz     = hn + (size_t)LSEQ * DM;     // L*2048
    float* xc     = xz + (size_t)LSEQ * 2 * DI; // L*DI
    float* dbc    = xc + (size_t)LSEQ * DI;     // L*64
    float* delta  = dbc + (size_t)LSEQ * 64;    // L*DI
    float* yb     = delta + (size_t)LSEQ * DI;  // L*DI
    float* hf     = yb + (size_t)LSEQ * DI;     // L*DM
    float* scores = hf + (size_t)LSEQ * DM;     // L
    float* wts    = scores + LSEQ;              // L
    float* pooled = wts + LSEQ;                 // DM
    float* c1     = pooled + DM;                // 256*16
    float* c2     = c1 + 256 * 16;              // 128*256
    float* c3     = c2 + 128 * 256;             // 64*1024
    float* c4     = c3 + 64 * 1024;             // 32*4096
    float* aprod  = c4 + 32 * 4096;             // NC*DI*NST
    float* hfin   = aprod + (size_t)NC * DI * NST;
    float* carry  = hfin + (size_t)NC * DI * NST;
    float* part   = carry + (size_t)NC * DI * NST;  // 16*DM

    // fc1 + gelu + pos-emb
    gemm64<<<dim3(DM / 64, LSEQ / 64), 256, 0, stream>>>(x, 1024, Wfc1, DM, hn, DM, 1024, 0);
    fc1_epi<<<LSEQ * DM / 256, 256, 0, stream>>>(hn, bfc1, coords, Wpos, bpos, h);

    for (int l = 0; l < 2; ++l) {
        rmsnorm_k<<<LSEQ, 256, 0, stream>>>(h, rms_w + l * DM, hn);
        gemm64<<<dim3(2 * DI / 64, LSEQ / 64), 256, 0, stream>>>(
            hn, DM, in_w + (size_t)l * DM * 2 * DI, 2 * DI, xz, 2 * DI, DM, 0);
        conv_silu_k<<<LSEQ * DI / 256, 256, 0, stream>>>(
            xz, conv_w + (size_t)l * DI * 4, conv_b + (size_t)l * DI, xc);
        gemm_rows4<<<LSEQ / 4, 256, 0, stream>>>(xc, DI, x_w + (size_t)l * DI * 64, dbc);
        gemm64<<<dim3(DI / 64, LSEQ / 64), 256, 0, stream>>>(
            dbc, 64, dt_w + (size_t)l * 32 * DI, DI, delta, DI, 32, 0);
        softplus_k<<<LSEQ * DI / 256, 256, 0, stream>>>(delta, dt_b + (size_t)l * DI);
        scan_p1<<<dim3(DI / 16, NC), 256, 0, stream>>>(
            delta, xc, dbc, A_log + (size_t)l * DI * NST, aprod, hfin);
        scan_carry<<<DI * NST / 256, 256, 0, stream>>>(aprod, hfin, carry);
        scan_p2<<<dim3(DI / 16, NC), 256, 0, stream>>>(
            delta, xc, dbc, xz, A_log + (size_t)l * DI * NST, Dp + (size_t)l * DI,
            carry, yb);
        gemm64<<<dim3(DM / 64, LSEQ / 64), 256, 0, stream>>>(
            yb, DI, out_w + (size_t)l * DI * DM, DM, h, DM, DI, 1);
    }

    layernorm_k<<<LSEQ, 256, 0, stream>>>(h, ln_w, ln_b, hf);
    attn_score_k<<<LSEQ, 128, 0, stream>>>(hf, Wa1, ba1, Wa2, ba2, scores);
    softmax_k<<<1, 1024, 0, stream>>>(scores, wts);
    pooled_p1<<<dim3(2, 16), 256, 0, stream>>>(wts, hf, part);
    pooled_p2<<<2, 256, 0, stream>>>(part, pooled);

    ct1_fast<<<256, 256, 0, stream>>>(pooled, ct1w, ct1b, c1);
    ct2_fast<<<dim3(16, 128), 256, 0, stream>>>(c1, ct2w, ct2b, c2);
    ctup_fast<<<dim3(32, 64), 256, 0, stream>>>(c2, ct3w, ct3b, c3, 128, 64, 16, 4, 1);
    ctup_fast<<<dim3(64, 32), 256, 0, stream>>>(c3, ct4w, ct4b, c4, 64, 32, 32, 5, 1);
    ctup_fast<<<dim3(128, 11), 256, 0, stream>>>(c4, ct5w, ct5b, (float*)d_out, 32, 11, 64, 6, 0);
}

// Round 5
// 793.729 us; speedup vs baseline: 3.1348x; 1.0918x over previous
//
#include <hip/hip_runtime.h>
#include <math.h>

#define LSEQ 2048
#define DM 512
#define DI 1024
#define NST 16
#define CHUNK 128
#define NC (LSEQ / CHUNK)

__device__ __forceinline__ float siluf(float v) { return v / (1.f + expf(-v)); }

// ---------------- generic fp32 GEMM: C[M,N] = A[M,K] @ B[K,N] (+C if accum) -----
// 64x64 tile, 256 threads, 4x4 micro-tile, BK=16.
__global__ __launch_bounds__(256) void gemm64(
    const float* __restrict__ A, int lda,
    const float* __restrict__ B, int ldb,
    float* __restrict__ C, int ldc,
    int K, int accum)
{
    __shared__ float As[16][68];
    __shared__ float Bs[16][68];
    const int tid = threadIdx.x;
    const int tx = tid & 15, ty = tid >> 4;
    const int m0 = blockIdx.y << 6, n0 = blockIdx.x << 6;
    const int arow = tid >> 2, akk = (tid & 3) << 2;
    const int bkr = tid >> 4, bnn = (tid & 15) << 2;
    const float* Ap = A + (size_t)(m0 + arow) * lda + akk;
    const float* Bp = B + (size_t)bkr * ldb + n0 + bnn;
    float acc[4][4] = {};
    for (int k0 = 0; k0 < K; k0 += 16) {
        float4 av = *(const float4*)(Ap + k0);
        float4 bv = *(const float4*)(Bp + (size_t)k0 * ldb);
        As[akk + 0][arow] = av.x;
        As[akk + 1][arow] = av.y;
        As[akk + 2][arow] = av.z;
        As[akk + 3][arow] = av.w;
        *(float4*)&Bs[bkr][bnn] = bv;
        __syncthreads();
#pragma unroll
        for (int kk = 0; kk < 16; ++kk) {
            float4 a = *(const float4*)&As[kk][ty << 2];
            float4 b = *(const float4*)&Bs[kk][tx << 2];
            acc[0][0] = fmaf(a.x, b.x, acc[0][0]);
            acc[0][1] = fmaf(a.x, b.y, acc[0][1]);
            acc[0][2] = fmaf(a.x, b.z, acc[0][2]);
            acc[0][3] = fmaf(a.x, b.w, acc[0][3]);
            acc[1][0] = fmaf(a.y, b.x, acc[1][0]);
            acc[1][1] = fmaf(a.y, b.y, acc[1][1]);
            acc[1][2] = fmaf(a.y, b.z, acc[1][2]);
            acc[1][3] = fmaf(a.y, b.w, acc[1][3]);
            acc[2][0] = fmaf(a.z, b.x, acc[2][0]);
            acc[2][1] = fmaf(a.z, b.y, acc[2][1]);
            acc[2][2] = fmaf(a.z, b.z, acc[2][2]);
            acc[2][3] = fmaf(a.z, b.w, acc[2][3]);
            acc[3][0] = fmaf(a.w, b.x, acc[3][0]);
            acc[3][1] = fmaf(a.w, b.y, acc[3][1]);
            acc[3][2] = fmaf(a.w, b.z, acc[3][2]);
            acc[3][3] = fmaf(a.w, b.w, acc[3][3]);
        }
        __syncthreads();
    }
#pragma unroll
    for (int i = 0; i < 4; ++i) {
        float* Cp = C + (size_t)(m0 + (ty << 2) + i) * ldc + n0 + (tx << 2);
        if (accum) {
            Cp[0] += acc[i][0]; Cp[1] += acc[i][1]; Cp[2] += acc[i][2]; Cp[3] += acc[i][3];
        } else {
            Cp[0] = acc[i][0]; Cp[1] = acc[i][1]; Cp[2] = acc[i][2]; Cp[3] = acc[i][3];
        }
    }
}

// ---------------- big-tile fp32 GEMM: 128x128 tile, 8x8 micro-tile, BK=8 --------
// M,N multiples of 128, K multiple of 8. 64 FMA per 4 ds_read_b128.
__global__ __launch_bounds__(256) void gemm128(
    const float* __restrict__ A, int lda,
    const float* __restrict__ B, int ldb,
    float* __restrict__ C, int ldc,
    int K, int accum)
{
    __shared__ float As[8][128];
    __shared__ float Bs[8][128];
    const int tid = threadIdx.x;
    const int tx = tid & 15, ty = tid >> 4;
    const int m0 = blockIdx.y << 7, n0 = blockIdx.x << 7;
    const int arow = tid >> 1, ak = (tid & 1) << 2;
    const int bkr = tid >> 5, bcol = (tid & 31) << 2;
    const float* Ap = A + (size_t)(m0 + arow) * lda + ak;
    const float* Bp = B + (size_t)bkr * ldb + n0 + bcol;
    float acc[8][8] = {};
    for (int k0 = 0; k0 < K; k0 += 8) {
        float4 av = *(const float4*)(Ap + k0);
        float4 bv = *(const float4*)(Bp + (size_t)k0 * ldb);
        As[ak + 0][arow] = av.x;
        As[ak + 1][arow] = av.y;
        As[ak + 2][arow] = av.z;
        As[ak + 3][arow] = av.w;
        *(float4*)&Bs[bkr][bcol] = bv;
        __syncthreads();
#pragma unroll
        for (int kk = 0; kk < 8; ++kk) {
            float4 a0 = *(const float4*)&As[kk][ty << 2];
            float4 a1 = *(const float4*)&As[kk][(ty << 2) + 64];
            float4 b0 = *(const float4*)&Bs[kk][tx << 2];
            float4 b1 = *(const float4*)&Bs[kk][(tx << 2) + 64];
            float a[8] = {a0.x, a0.y, a0.z, a0.w, a1.x, a1.y, a1.z, a1.w};
            float b[8] = {b0.x, b0.y, b0.z, b0.w, b1.x, b1.y, b1.z, b1.w};
#pragma unroll
            for (int i = 0; i < 8; ++i)
#pragma unroll
                for (int j = 0; j < 8; ++j)
                    acc[i][j] = fmaf(a[i], b[j], acc[i][j]);
        }
        __syncthreads();
    }
#pragma unroll
    for (int qi = 0; qi < 2; ++qi)
#pragma unroll
        for (int i = 0; i < 4; ++i) {
            const int row = m0 + (ty << 2) + i + (qi << 6);
            float* Cp = C + (size_t)row * ldc + n0 + (tx << 2);
            if (accum) {
#pragma unroll
                for (int j = 0; j < 4; ++j) {
                    Cp[j] += acc[(qi << 2) + i][j];
                    Cp[64 + j] += acc[(qi << 2) + i][4 + j];
                }
            } else {
#pragma unroll
                for (int j = 0; j < 4; ++j) {
                    Cp[j] = acc[(qi << 2) + i][j];
                    Cp[64 + j] = acc[(qi << 2) + i][4 + j];
                }
            }
        }
}

// ---------------- x_proj split-K: [2048,1024]@[1024,64] -> partials -------------
// grid (8 k-splits, 32 m-tiles); each block 64x64x128 partial tile.
__global__ __launch_bounds__(256) void xproj_splitk(
    const float* __restrict__ A, const float* __restrict__ B,
    float* __restrict__ part)
{
    __shared__ float As[16][68];
    __shared__ float Bs[16][68];
    const int tid = threadIdx.x;
    const int tx = tid & 15, ty = tid >> 4;
    const int ks = blockIdx.x;
    const int m0 = blockIdx.y << 6;
    const int arow = tid >> 2, ak = (tid & 3) << 2;
    const int bkr = tid >> 4, bcol = (tid & 15) << 2;
    const int kbase = ks << 7;
    const float* Ap = A + (size_t)(m0 + arow) * DI + kbase + ak;
    const float* Bp = B + (size_t)(kbase + bkr) * 64 + bcol;
    float acc[4][4] = {};
    for (int k0 = 0; k0 < 128; k0 += 16) {
        float4 av = *(const float4*)(Ap + k0);
        float4 bv = *(const float4*)(Bp + k0 * 64);
        As[ak + 0][arow] = av.x;
        As[ak + 1][arow] = av.y;
        As[ak + 2][arow] = av.z;
        As[ak + 3][arow] = av.w;
        *(float4*)&Bs[bkr][bcol] = bv;
        __syncthreads();
#pragma unroll
        for (int kk = 0; kk < 16; ++kk) {
            float4 a = *(const float4*)&As[kk][ty << 2];
            float4 b = *(const float4*)&Bs[kk][tx << 2];
            acc[0][0] = fmaf(a.x, b.x, acc[0][0]);
            acc[0][1] = fmaf(a.x, b.y, acc[0][1]);
            acc[0][2] = fmaf(a.x, b.z, acc[0][2]);
            acc[0][3] = fmaf(a.x, b.w, acc[0][3]);
            acc[1][0] = fmaf(a.y, b.x, acc[1][0]);
            acc[1][1] = fmaf(a.y, b.y, acc[1][1]);
            acc[1][2] = fmaf(a.y, b.z, acc[1][2]);
            acc[1][3] = fmaf(a.y, b.w, acc[1][3]);
            acc[2][0] = fmaf(a.z, b.x, acc[2][0]);
            acc[2][1] = fmaf(a.z, b.y, acc[2][1]);
            acc[2][2] = fmaf(a.z, b.z, acc[2][2]);
            acc[2][3] = fmaf(a.z, b.w, acc[2][3]);
            acc[3][0] = fmaf(a.w, b.x, acc[3][0]);
            acc[3][1] = fmaf(a.w, b.y, acc[3][1]);
            acc[3][2] = fmaf(a.w, b.z, acc[3][2]);
            acc[3][3] = fmaf(a.w, b.w, acc[3][3]);
        }
        __syncthreads();
    }
#pragma unroll
    for (int i = 0; i < 4; ++i) {
        float* Cp = part + ((size_t)ks * LSEQ + m0 + (ty << 2) + i) * 64 + (tx << 2);
        Cp[0] = acc[i][0]; Cp[1] = acc[i][1]; Cp[2] = acc[i][2]; Cp[3] = acc[i][3];
    }
}

__global__ __launch_bounds__(256) void xproj_reduce(
    const float* __restrict__ part, float* __restrict__ dbc)
{
    const int idx = blockIdx.x * 256 + threadIdx.x;   // LSEQ*64
    float s = 0.f;
#pragma unroll
    for (int ks = 0; ks < 8; ++ks) s += part[(size_t)ks * LSEQ * 64 + idx];
    dbc[idx] = s;
}

// ---------------- fc1 epilogue: gelu(tmp + b) + coords@Wpos + bpos --------------
__global__ __launch_bounds__(256) void fc1_epi(
    const float* __restrict__ tmp, const float* __restrict__ bfc1,
    const float* __restrict__ coords, const float* __restrict__ Wpos,
    const float* __restrict__ bpos, float* __restrict__ h)
{
    int idx = blockIdx.x * 256 + threadIdx.x;   // L*DM
    int t = idx >> 9, j = idx & 511;
    float v = tmp[idx] + bfc1[j];
    float g = 0.5f * v * (1.f + erff(v * 0.70710678118654752f));
    h[idx] = g + coords[2 * t] * Wpos[j] + coords[2 * t + 1] * Wpos[DM + j] + bpos[j];
}

// ---------------- RMSNorm over last dim (512) -----------------------------------
__global__ __launch_bounds__(256) void rmsnorm_k(
    const float* __restrict__ h, const float* __restrict__ w, float* __restrict__ out)
{
    const int t = blockIdx.x, tid = threadIdx.x;
    float a = h[(size_t)t * DM + tid];
    float b = h[(size_t)t * DM + 256 + tid];
    float ss = a * a + b * b;
#pragma unroll
    for (int off = 1; off < 64; off <<= 1) ss += __shfl_xor(ss, off);
    __shared__ float red[4];
    if ((tid & 63) == 0) red[tid >> 6] = ss;
    __syncthreads();
    float tot = red[0] + red[1] + red[2] + red[3];
    float inv = rsqrtf(tot * (1.f / DM) + 1e-5f);
    out[(size_t)t * DM + tid] = a * inv * w[tid];
    out[(size_t)t * DM + 256 + tid] = b * inv * w[256 + tid];
}

// ---------------- LayerNorm over last dim (512) ---------------------------------
__global__ __launch_bounds__(256) void layernorm_k(
    const float* __restrict__ h, const float* __restrict__ w,
    const float* __restrict__ bb, float* __restrict__ out)
{
    const int t = blockIdx.x, tid = threadIdx.x;
    float a = h[(size_t)t * DM + tid];
    float b = h[(size_t)t * DM + 256 + tid];
    float s = a + b;
#pragma unroll
    for (int off = 1; off < 64; off <<= 1) s += __shfl_xor(s, off);
    __shared__ float red1[4];
    if ((tid & 63) == 0) red1[tid >> 6] = s;
    __syncthreads();
    float mean = (red1[0] + red1[1] + red1[2] + red1[3]) * (1.f / DM);
    float da = a - mean, db = b - mean;
    float vs = da * da + db * db;
#pragma unroll
    for (int off = 1; off < 64; off <<= 1) vs += __shfl_xor(vs, off);
    __shared__ float red2[4];
    if ((tid & 63) == 0) red2[tid >> 6] = vs;
    __syncthreads();
    float var = (red2[0] + red2[1] + red2[2] + red2[3]) * (1.f / DM);
    float inv = rsqrtf(var + 1e-5f);
    out[(size_t)t * DM + tid] = da * inv * w[tid] + bb[tid];
    out[(size_t)t * DM + 256 + tid] = db * inv * w[256 + tid] + bb[256 + tid];
}

// ---------------- causal depthwise conv (k=4) + SiLU ----------------------------
__global__ __launch_bounds__(256) void conv_silu_k(
    const float* __restrict__ xz, const float* __restrict__ cw,
    const float* __restrict__ cb, float* __restrict__ xc)
{
    int idx = blockIdx.x * 256 + threadIdx.x;   // L*DI
    int t = idx >> 10, c = idx & 1023;
    float w0 = cw[c * 4], w1 = cw[c * 4 + 1], w2 = cw[c * 4 + 2], w3 = cw[c * 4 + 3];
    float s = cb[c];
    if (t >= 3) s = fmaf(xz[(size_t)(t - 3) * 2048 + c], w0, s);
    if (t >= 2) s = fmaf(xz[(size_t)(t - 2) * 2048 + c], w1, s);
    if (t >= 1) s = fmaf(xz[(size_t)(t - 1) * 2048 + c], w2, s);
    s = fmaf(xz[(size_t)t * 2048 + c], w3, s);
    xc[idx] = siluf(s);
}

// ---------------- softplus(delta + dtb) in place --------------------------------
__global__ __launch_bounds__(256) void softplus_k(
    float* __restrict__ delta, const float* __restrict__ dtb)
{
    int idx = blockIdx.x * 256 + threadIdx.x;   // L*DI
    int d = idx & 1023;
    float v = delta[idx] + dtb[d];
    delta[idx] = fmaxf(v, 0.f) + log1pf(expf(-fabsf(v)));
}

// ===================== chunked parallel selective scan ==========================
__global__ __launch_bounds__(256) void scan_p1(
    const float* __restrict__ delta, const float* __restrict__ xc,
    const float* __restrict__ dbc, const float* __restrict__ alog,
    float* __restrict__ aprod, float* __restrict__ hfin)
{
    __shared__ float sD[CHUNK][16], sX[CHUNK][16], sB[CHUNK][16];
    const int tid = threadIdx.x;
    const int g = tid >> 4, n = tid & 15;
    const int d0 = blockIdx.x << 4;
    const int c = blockIdx.y;
    const int t0 = c * CHUNK;
    const int d = d0 + g;
    const float An = -expf(alog[d * NST + n]);
    for (int i = tid; i < CHUNK * 16; i += 256) {
        int r = i >> 4, cc = i & 15;
        sD[r][cc] = delta[(size_t)(t0 + r) * DI + d0 + cc];
        sX[r][cc] = xc[(size_t)(t0 + r) * DI + d0 + cc];
        sB[r][cc] = dbc[(size_t)(t0 + r) * 64 + 32 + cc];
    }
    __syncthreads();
    float h = 0.f, ap = 1.f;
    for (int i = 0; i < CHUNK; ++i) {
        float dl = sD[i][g], xv = sX[i][g];
        float a = expf(dl * An);
        h = fmaf(a, h, dl * xv * sB[i][n]);
        ap *= a;
    }
    size_t idx = ((size_t)c * DI + d) * NST + n;
    aprod[idx] = ap;
    hfin[idx] = h;
}

__global__ __launch_bounds__(256) void scan_carry(
    const float* __restrict__ aprod, const float* __restrict__ hfin,
    float* __restrict__ carry)
{
    const int dn = blockIdx.x * 256 + threadIdx.x;   // DI*NST
    float h = 0.f;
    carry[dn] = 0.f;
#pragma unroll
    for (int c = 0; c < NC - 1; ++c) {
        h = fmaf(aprod[(size_t)c * DI * NST + dn], h, hfin[(size_t)c * DI * NST + dn]);
        carry[(size_t)(c + 1) * DI * NST + dn] = h;
    }
}

__global__ __launch_bounds__(256) void scan_p2(
    const float* __restrict__ delta, const float* __restrict__ xc,
    const float* __restrict__ dbc, const float* __restrict__ xz,
    const float* __restrict__ alog, const float* __restrict__ Dp,
    const float* __restrict__ carry, float* __restrict__ y)
{
    __shared__ float sD[CHUNK][16], sX[CHUNK][16], sB[CHUNK][16], sC[CHUNK][16], sZ[CHUNK][16];
    const int tid = threadIdx.x;
    const int g = tid >> 4, n = tid & 15;
    const int d0 = blockIdx.x << 4;
    const int c = blockIdx.y;
    const int t0 = c * CHUNK;
    const int d = d0 + g;
    const float An = -expf(alog[d * NST + n]);
    const float Dd = Dp[d];
    for (int i = tid; i < CHUNK * 16; i += 256) {
        int r = i >> 4, cc = i & 15;
        sD[r][cc] = delta[(size_t)(t0 + r) * DI + d0 + cc];
        sX[r][cc] = xc[(size_t)(t0 + r) * DI + d0 + cc];
        sB[r][cc] = dbc[(size_t)(t0 + r) * 64 + 32 + cc];
        sC[r][cc] = dbc[(size_t)(t0 + r) * 64 + 48 + cc];
        sZ[r][cc] = xz[(size_t)(t0 + r) * 2048 + 1024 + d0 + cc];
    }
    __syncthreads();
    float h = carry[((size_t)c * DI + d) * NST + n];
    for (int i = 0; i < CHUNK; ++i) {
        float dl = sD[i][g], xv = sX[i][g];
        float a = expf(dl * An);
        h = fmaf(a, h, dl * xv * sB[i][n]);
        float p = h * sC[i][n];
        p += __shfl_xor(p, 1, 16);
        p += __shfl_xor(p, 2, 16);
        p += __shfl_xor(p, 4, 16);
        p += __shfl_xor(p, 8, 16);
        if (n == 0) {
            float yv = p + xv * Dd;
            float zz = sZ[i][g];
            y[(size_t)(t0 + i) * DI + d] = yv * siluf(zz);
        }
    }
}

// ---------------- attn epilogue: scores = tanh(amx+ba1)@Wa2 + ba2 ---------------
// block 256 = 4 rows x 64 lanes (2 cols each)
__global__ __launch_bounds__(256) void attn_fin(
    const float* __restrict__ amx, const float* __restrict__ ba1,
    const float* __restrict__ Wa2, const float* __restrict__ ba2,
    float* __restrict__ scores)
{
    const int tid = threadIdx.x;
    const int row = blockIdx.x * 4 + (tid >> 6);
    const int lane = tid & 63;
    float v = tanhf(amx[(size_t)row * 128 + lane] + ba1[lane]) * Wa2[lane]
            + tanhf(amx[(size_t)row * 128 + 64 + lane] + ba1[64 + lane]) * Wa2[64 + lane];
#pragma unroll
    for (int off = 1; off < 64; off <<= 1) v += __shfl_xor(v, off);
    if (lane == 0) scores[row] = v + ba2[0];
}

// ---------------- softmax over 2048 scores (one block) --------------------------
__global__ __launch_bounds__(1024) void softmax_k(
    const float* __restrict__ s, float* __restrict__ w)
{
    const int tid = threadIdx.x;
    __shared__ float red[16];
    float m = fmaxf(s[tid], s[tid + 1024]);
#pragma unroll
    for (int off = 1; off < 64; off <<= 1) m = fmaxf(m, __shfl_xor(m, off));
    if ((tid & 63) == 0) red[tid >> 6] = m;
    __syncthreads();
    if (tid < 64) {
        float mm = (tid < 16) ? red[tid] : -1e30f;
#pragma unroll
        for (int off = 1; off < 16; off <<= 1) mm = fmaxf(mm, __shfl_xor(mm, off));
        if (tid == 0) red[0] = mm;
    }
    __syncthreads();
    const float gm = red[0];
    __syncthreads();
    float e0 = expf(s[tid] - gm), e1 = expf(s[tid + 1024] - gm);
    float sum = e0 + e1;
#pragma unroll
    for (int off = 1; off < 64; off <<= 1) sum += __shfl_xor(sum, off);
    __shared__ float red2[16];
    if ((tid & 63) == 0) red2[tid >> 6] = sum;
    __syncthreads();
    if (tid < 64) {
        float ss = (tid < 16) ? red2[tid] : 0.f;
#pragma unroll
        for (int off = 1; off < 16; off <<= 1) ss += __shfl_xor(ss, off);
        if (tid == 0) red2[0] = ss;
    }
    __syncthreads();
    float inv = 1.f / red2[0];
    w[tid] = e0 * inv;
    w[tid + 1024] = e1 * inv;
}

// ---------------- pooled: two-stage  part[tc,j] then sum ------------------------
__global__ __launch_bounds__(256) void pooled_p1(
    const float* __restrict__ wts, const float* __restrict__ hf, float* __restrict__ part)
{
    const int j = blockIdx.x * 256 + threadIdx.x;   // 0..511
    const int tc = blockIdx.y;                       // 16 chunks of 128
    float acc = 0.f;
    const int t0 = tc * 128;
    for (int t = t0; t < t0 + 128; ++t) acc = fmaf(wts[t], hf[(size_t)t * DM + j], acc);
    part[(size_t)tc * DM + j] = acc;
}

__global__ __launch_bounds__(256) void pooled_p2(
    const float* __restrict__ part, float* __restrict__ pooled)
{
    const int j = blockIdx.x * 256 + threadIdx.x;
    float acc = 0.f;
#pragma unroll
    for (int tc = 0; tc < 16; ++tc) acc += part[(size_t)tc * DM + j];
    pooled[j] = acc;
}

// ---------------- ct1: ConvT 1x1->4x4 (s=1,p=0), 512->256, relu -----------------
__global__ __launch_bounds__(256) void ct1_fast(
    const float* __restrict__ feat, const float* __restrict__ w,
    const float* __restrict__ b, float* __restrict__ out)
{
    __shared__ float sf[512];
    __shared__ float sRed[256];
    const int o = blockIdx.x, tid = threadIdx.x;
    sf[tid] = feat[tid];
    sf[tid + 256] = feat[tid + 256];
    __syncthreads();
    const int p = tid & 15, g = tid >> 4;
    float acc = 0.f;
#pragma unroll 8
    for (int ci = g * 32; ci < g * 32 + 32; ++ci)
        acc = fmaf(sf[ci], w[ci * 4096 + (o << 4) + p], acc);
    sRed[tid] = acc;
    __syncthreads();
    if (g == 0) {
        float s = b[o];
#pragma unroll
        for (int gg = 0; gg < 16; ++gg) s += sRed[gg * 16 + p];
        out[(o << 4) + p] = fmaxf(s, 0.f);
    }
}

// ---------------- ct2: ConvT 4x4->16x16 (s=4,p=0), 256->128, relu ---------------
__global__ __launch_bounds__(256) void ct2_fast(
    const float* __restrict__ in, const float* __restrict__ w,
    const float* __restrict__ b, float* __restrict__ out)
{
    __shared__ float sI[1024];   // [ci][ix]
    __shared__ float sW[1024];   // [ci][kx]
    __shared__ float sRed[256];
    const int yy = blockIdx.x, o = blockIdx.y, tid = threadIdx.x;
    const int iy = yy >> 2, ky = yy & 3;
    for (int i = tid; i < 1024; i += 256) {
        int ci = i >> 2, q = i & 3;
        sI[i] = in[(ci << 4) + (iy << 2) + q];
        sW[i] = w[ci * 2048 + (o << 4) + (ky << 2) + q];
    }
    __syncthreads();
    const int xx = tid & 15, g = tid >> 4;
    const int ix = xx >> 2, kx = xx & 3;
    float acc = 0.f;
#pragma unroll 8
    for (int ci = g * 16; ci < g * 16 + 16; ++ci)
        acc = fmaf(sI[(ci << 2) + ix], sW[(ci << 2) + kx], acc);
    sRed[tid] = acc;
    __syncthreads();
    if (g == 0) {
        float s = b[o];
#pragma unroll
        for (int gg = 0; gg < 16; ++gg) s += sRed[gg * 16 + xx];
        out[(o << 8) + (yy << 4) + xx] = fmaxf(s, 0.f);
    }
}

// ---------------- ConvT (k=4,s=2,p=1) Hin->2*Hin, LDS-staged --------------------
__global__ __launch_bounds__(256) void ctup_fast(
    const float* __restrict__ in, const float* __restrict__ w,
    const float* __restrict__ b, float* __restrict__ out,
    int Cin, int Cout, int Hin, int hshift, int relu)
{
    __shared__ float sIn[4608];   // 2 rows x Cin x (Hin+2), max 2*128*18
    __shared__ float sW[2048];    // Cin x 16
    __shared__ float sRed[256];
    const int tid = threadIdx.x;
    const int yy = blockIdx.x, o = blockIdx.y;
    const int Hout = Hin << 1;
    const int ST = Hin + 2;
    const int houtshift = hshift + 1;

    const int ky0 = (yy + 1) & 1;
    const int iy0 = (yy + 1 - ky0) >> 1;
    const int iy1 = iy0 - 1;
    const int row_elems = Cin * ST;

    for (int i = tid; i < 2 * row_elems; i += 256) sIn[i] = 0.f;
    __syncthreads();
    const int nload = Cin << hshift;
    if (iy0 < Hin) {
        const float* src = in + ((size_t)iy0 << hshift);
        for (int i = tid; i < nload; i += 256) {
            int ci = i >> hshift, col = i & (Hin - 1);
            sIn[ci * ST + 1 + col] = src[((size_t)ci << (2 * hshift)) + col];
        }
    }
    if (iy1 >= 0) {
        const float* src = in + ((size_t)iy1 << hshift);
        for (int i = tid; i < nload; i += 256) {
            int ci = i >> hshift, col = i & (Hin - 1);
            sIn[row_elems + ci * ST + 1 + col] = src[((size_t)ci << (2 * hshift)) + col];
        }
    }
    for (int i = tid; i < (Cin << 4); i += 256)
        sW[i] = w[(size_t)(i >> 4) * (Cout << 4) + (o << 4) + (i & 15)];
    __syncthreads();

    const int xx = tid & (Hout - 1);
    const int g = tid >> houtshift;
    const int kx0 = (xx + 1) & 1;
    const int ix0 = (xx + 1 - kx0) >> 1;
    const int k00 = (ky0 << 2) + kx0;

    float acc = 0.f;
    const float* in1 = sIn + row_elems;
#pragma unroll 4
    for (int ci = g * 16; ci < g * 16 + 16; ++ci) {
        const int base = ci * ST + ix0;
        const float* wr = &sW[ci << 4];
        float i00 = sIn[base + 1], i01 = sIn[base];
        float i10 = in1[base + 1], i11 = in1[base];
        acc = fmaf(i00, wr[k00], acc);
        acc = fmaf(i01, wr[k00 + 2], acc);
        acc = fmaf(i10, wr[k00 + 8], acc);
        acc = fmaf(i11, wr[k00 + 10], acc);
    }
    sRed[tid] = acc;
    __syncthreads();
    if (g == 0) {
        float s = b[o];
        const int XG = 256 >> houtshift;
        for (int gg = 0; gg < XG; ++gg) s += sRed[(gg << houtshift) + xx];
        out[(size_t)o * Hout * Hout + (size_t)yy * Hout + xx] = relu ? fmaxf(s, 0.f) : s;
    }
}

extern "C" void kernel_launch(void* const* d_in, const int* in_sizes, int n_in,
                              void* d_out, int out_size, void* d_ws, size_t ws_size,
                              hipStream_t stream)
{
    const float* x      = (const float*)d_in[0];
    const float* coords = (const float*)d_in[1];
    const float* Wfc1   = (const float*)d_in[2];
    const float* bfc1   = (const float*)d_in[3];
    const float* Wpos   = (const float*)d_in[4];
    const float* bpos   = (const float*)d_in[5];
    const float* in_w   = (const float*)d_in[6];
    const float* conv_w = (const float*)d_in[7];
    const float* conv_b = (const float*)d_in[8];
    const float* x_w    = (const float*)d_in[9];
    const float* dt_w   = (const float*)d_in[10];
    const float* dt_b   = (const float*)d_in[11];
    const float* A_log  = (const float*)d_in[12];
    const float* Dp     = (const float*)d_in[13];
    const float* out_w  = (const float*)d_in[14];
    const float* rms_w  = (const float*)d_in[15];
    const float* ln_w   = (const float*)d_in[16];
    const float* ln_b   = (const float*)d_in[17];
    const float* Wa1    = (const float*)d_in[18];
    const float* ba1    = (const float*)d_in[19];
    const float* Wa2    = (const float*)d_in[20];
    const float* ba2    = (const float*)d_in[21];
    const float* ct1w   = (const float*)d_in[22];
    const float* ct1b   = (const float*)d_in[23];
    const float* ct2w   = (const float*)d_in[24];
    const float* ct2b   = (const float*)d_in[25];
    const float* ct3w   = (const float*)d_in[26];
    const float* ct3b   = (const float*)d_in[27];
    const float* ct4w   = (const float*)d_in[28];
    const float* ct4b   = (const float*)d_in[29];
    const float* ct5w   = (const float*)d_in[30];
    const float* ct5b   = (const float*)d_in[31];

    // workspace layout (floats)
    float* ws     = (float*)d_ws;
    float* h      = ws;                         // L*DM
    float* hn     = h + (size_t)LSEQ * DM;      // L*DM (also fc1 temp)
    float* xz     = hn + (size_t)LSEQ * DM;     // L*2048 (aliased as amx later)
    float* xc     = xz + (size_t)LSEQ * 2 * DI; // L*DI
    float* dbc    = xc + (size_t)LSEQ * DI;     // L*64
    float* delta  = dbc + (size_t)LSEQ * 64;    // L*DI
    float* yb     = delta + (size_t)LSEQ * DI;  // L*DI (aliased as split-K partials)
    float* hf     = yb + (size_t)LSEQ * DI;     // L*DM
    float* scores = hf + (size_t)LSEQ * DM;     // L
    float* wts    = scores + LSEQ;              // L
    float* pooled = wts + LSEQ;                 // DM
    float* c1     = pooled + DM;                // 256*16
    float* c2     = c1 + 256 * 16;              // 128*256
    float* c3     = c2 + 128 * 256;             // 64*1024
    float* c4     = c3 + 64 * 1024;             // 32*4096
    float* aprod  = c4 + 32 * 4096;             // NC*DI*NST
    float* hfin   = aprod + (size_t)NC * DI * NST;
    float* carry  = hfin + (size_t)NC * DI * NST;
    float* part   = carry + (size_t)NC * DI * NST;  // 16*DM (pooled partials)
    float* partk  = yb;                          // alias: x_proj split-K partials (8*L*64 = L*512 < L*DI)
    float* amx    = xz;                          // alias: attn pre-act [L,128]

    // fc1 + gelu + pos-emb
    gemm64<<<dim3(DM / 64, LSEQ / 64), 256, 0, stream>>>(x, 1024, Wfc1, DM, hn, DM, 1024, 0);
    fc1_epi<<<LSEQ * DM / 256, 256, 0, stream>>>(hn, bfc1, coords, Wpos, bpos, h);

    for (int l = 0; l < 2; ++l) {
        rmsnorm_k<<<LSEQ, 256, 0, stream>>>(h, rms_w + l * DM, hn);
        gemm128<<<dim3(2 * DI / 128, LSEQ / 128), 256, 0, stream>>>(
            hn, DM, in_w + (size_t)l * DM * 2 * DI, 2 * DI, xz, 2 * DI, DM, 0);
        conv_silu_k<<<LSEQ * DI / 256, 256, 0, stream>>>(
            xz, conv_w + (size_t)l * DI * 4, conv_b + (size_t)l * DI, xc);
        xproj_splitk<<<dim3(8, LSEQ / 64), 256, 0, stream>>>(
            xc, x_w + (size_t)l * DI * 64, partk);
        xproj_reduce<<<LSEQ * 64 / 256, 256, 0, stream>>>(partk, dbc);
        gemm64<<<dim3(DI / 64, LSEQ / 64), 256, 0, stream>>>(
            dbc, 64, dt_w + (size_t)l * 32 * DI, DI, delta, DI, 32, 0);
        softplus_k<<<LSEQ * DI / 256, 256, 0, stream>>>(delta, dt_b + (size_t)l * DI);
        scan_p1<<<dim3(DI / 16, NC), 256, 0, stream>>>(
            delta, xc, dbc, A_log + (size_t)l * DI * NST, aprod, hfin);
        scan_carry<<<DI * NST / 256, 256, 0, stream>>>(aprod, hfin, carry);
        scan_p2<<<dim3(DI / 16, NC), 256, 0, stream>>>(
            delta, xc, dbc, xz, A_log + (size_t)l * DI * NST, Dp + (size_t)l * DI,
            carry, yb);
        gemm64<<<dim3(DM / 64, LSEQ / 64), 256, 0, stream>>>(
            yb, DI, out_w + (size_t)l * DI * DM, DM, h, DM, DI, 1);
    }

    layernorm_k<<<LSEQ, 256, 0, stream>>>(h, ln_w, ln_b, hf);
    gemm64<<<dim3(2, LSEQ / 64), 256, 0, stream>>>(hf, DM, Wa1, 128, amx, 128, DM, 0);
    attn_fin<<<LSEQ / 4, 256, 0, stream>>>(amx, ba1, Wa2, ba2, scores);
    softmax_k<<<1, 1024, 0, stream>>>(scores, wts);
    pooled_p1<<<dim3(2, 16), 256, 0, stream>>>(wts, hf, part);
    pooled_p2<<<2, 256, 0, stream>>>(part, pooled);

    ct1_fast<<<256, 256, 0, stream>>>(pooled, ct1w, ct1b, c1);
    ct2_fast<<<dim3(16, 128), 256, 0, stream>>>(c1, ct2w, ct2b, c2);
    ctup_fast<<<dim3(32, 64), 256, 0, stream>>>(c2, ct3w, ct3b, c3, 128, 64, 16, 4, 1);
    ctup_fast<<<dim3(64, 32), 256, 0, stream>>>(c3, ct4w, ct4b, c4, 64, 32, 32, 5, 1);
    ctup_fast<<<dim3(128, 11), 256, 0, stream>>>(c4, ct5w, ct5b, (float*)d_out, 32, 11, 64, 6, 0);
}

// Round 6
// 670.168 us; speedup vs baseline: 3.7128x; 1.1844x over previous
//
#include <hip/hip_runtime.h>
#include <math.h>

#define LSEQ 2048
#define DM 512
#define DI 1024
#define NST 16
#define CHUNK 128
#define NC (LSEQ / CHUNK)

__device__ __forceinline__ float siluf(float v) { return v / (1.f + expf(-v)); }

// ---------------- gemm_mt: 64(M)x128(N) tile, BK=16, 256 thr, 4x8 micro ---------
// split-K via gridDim.z: block z computes K-range [z*K/nz, (z+1)*K/nz) and writes
// its partial to out + z*Mtot*ldc. nz==1 -> direct full result.
// Reg-prefetch double buffer hides global latency under FMA work.
__global__ __launch_bounds__(256) void gemm_mt(
    const float* __restrict__ A, int lda,
    const float* __restrict__ B, int ldb,
    float* __restrict__ out, int ldc, int Ktot)
{
    __shared__ float As[16][68];
    __shared__ float Bs[16][132];
    const int tid = threadIdx.x;
    const int tx = tid & 15, ty = tid >> 4;
    const int n0 = blockIdx.x << 7, m0 = blockIdx.y << 6;
    const int z = blockIdx.z, nz = gridDim.z;
    const int Kz = Ktot / nz, kb = z * Kz;
    const int arow = tid >> 2, ak = (tid & 3) << 2;
    const int bkr = tid >> 5, bcol = (tid & 31) << 2;
    const float* Ap = A + (size_t)(m0 + arow) * lda + kb + ak;
    const float* Bp = B + (size_t)(kb + bkr) * ldb + n0 + bcol;
    float acc[4][8] = {};
    float4 av = *(const float4*)(Ap);
    float4 bv0 = *(const float4*)(Bp);
    float4 bv1 = *(const float4*)(Bp + (size_t)8 * ldb);
    for (int k0 = 0; k0 < Kz; k0 += 16) {
        As[ak + 0][arow] = av.x;
        As[ak + 1][arow] = av.y;
        As[ak + 2][arow] = av.z;
        As[ak + 3][arow] = av.w;
        *(float4*)&Bs[bkr][bcol] = bv0;
        *(float4*)&Bs[bkr + 8][bcol] = bv1;
        __syncthreads();
        if (k0 + 16 < Kz) {
            av = *(const float4*)(Ap + k0 + 16);
            bv0 = *(const float4*)(Bp + (size_t)(k0 + 16) * ldb);
            bv1 = *(const float4*)(Bp + (size_t)(k0 + 24) * ldb);
        }
#pragma unroll
        for (int kk = 0; kk < 16; ++kk) {
            float4 a = *(const float4*)&As[kk][ty << 2];
            float4 b0 = *(const float4*)&Bs[kk][tx << 2];
            float4 b1 = *(const float4*)&Bs[kk][(tx << 2) + 64];
            float a4[4] = {a.x, a.y, a.z, a.w};
            float b8[8] = {b0.x, b0.y, b0.z, b0.w, b1.x, b1.y, b1.z, b1.w};
#pragma unroll
            for (int i = 0; i < 4; ++i)
#pragma unroll
                for (int j = 0; j < 8; ++j)
                    acc[i][j] = fmaf(a4[i], b8[j], acc[i][j]);
        }
        __syncthreads();
    }
    const int Mtot = gridDim.y << 6;
    float* op = out + (size_t)z * Mtot * ldc;
#pragma unroll
    for (int i = 0; i < 4; ++i) {
        float* Cp = op + (size_t)(m0 + (ty << 2) + i) * ldc + n0 + (tx << 2);
        *(float4*)Cp = make_float4(acc[i][0], acc[i][1], acc[i][2], acc[i][3]);
        *(float4*)(Cp + 64) = make_float4(acc[i][4], acc[i][5], acc[i][6], acc[i][7]);
    }
}

// ---------------- split-K reduce: out = (or +=) sum_z part[z] -------------------
__global__ __launch_bounds__(256) void sk_reduce(
    const float* __restrict__ part, float* __restrict__ out, int S, int nz, int add)
{
    const int idx = blockIdx.x * 256 + threadIdx.x;
    if (idx >= S) return;
    float s = 0.f;
    for (int zz = 0; zz < nz; ++zz) s += part[(size_t)zz * S + idx];
    if (add) out[idx] += s; else out[idx] = s;
}

// ---------------- generic fp32 GEMM: 64x64 tile, 4x4 micro, BK=16 ---------------
__global__ __launch_bounds__(256) void gemm64(
    const float* __restrict__ A, int lda,
    const float* __restrict__ B, int ldb,
    float* __restrict__ C, int ldc,
    int K, int accum)
{
    __shared__ float As[16][68];
    __shared__ float Bs[16][68];
    const int tid = threadIdx.x;
    const int tx = tid & 15, ty = tid >> 4;
    const int m0 = blockIdx.y << 6, n0 = blockIdx.x << 6;
    const int arow = tid >> 2, akk = (tid & 3) << 2;
    const int bkr = tid >> 4, bnn = (tid & 15) << 2;
    const float* Ap = A + (size_t)(m0 + arow) * lda + akk;
    const float* Bp = B + (size_t)bkr * ldb + n0 + bnn;
    float acc[4][4] = {};
    for (int k0 = 0; k0 < K; k0 += 16) {
        float4 av = *(const float4*)(Ap + k0);
        float4 bv = *(const float4*)(Bp + (size_t)k0 * ldb);
        As[akk + 0][arow] = av.x;
        As[akk + 1][arow] = av.y;
        As[akk + 2][arow] = av.z;
        As[akk + 3][arow] = av.w;
        *(float4*)&Bs[bkr][bnn] = bv;
        __syncthreads();
#pragma unroll
        for (int kk = 0; kk < 16; ++kk) {
            float4 a = *(const float4*)&As[kk][ty << 2];
            float4 b = *(const float4*)&Bs[kk][tx << 2];
            acc[0][0] = fmaf(a.x, b.x, acc[0][0]);
            acc[0][1] = fmaf(a.x, b.y, acc[0][1]);
            acc[0][2] = fmaf(a.x, b.z, acc[0][2]);
            acc[0][3] = fmaf(a.x, b.w, acc[0][3]);
            acc[1][0] = fmaf(a.y, b.x, acc[1][0]);
            acc[1][1] = fmaf(a.y, b.y, acc[1][1]);
            acc[1][2] = fmaf(a.y, b.z, acc[1][2]);
            acc[1][3] = fmaf(a.y, b.w, acc[1][3]);
            acc[2][0] = fmaf(a.z, b.x, acc[2][0]);
            acc[2][1] = fmaf(a.z, b.y, acc[2][1]);
            acc[2][2] = fmaf(a.z, b.z, acc[2][2]);
            acc[2][3] = fmaf(a.z, b.w, acc[2][3]);
            acc[3][0] = fmaf(a.w, b.x, acc[3][0]);
            acc[3][1] = fmaf(a.w, b.y, acc[3][1]);
            acc[3][2] = fmaf(a.w, b.z, acc[3][2]);
            acc[3][3] = fmaf(a.w, b.w, acc[3][3]);
        }
        __syncthreads();
    }
#pragma unroll
    for (int i = 0; i < 4; ++i) {
        float* Cp = C + (size_t)(m0 + (ty << 2) + i) * ldc + n0 + (tx << 2);
        if (accum) {
            Cp[0] += acc[i][0]; Cp[1] += acc[i][1]; Cp[2] += acc[i][2]; Cp[3] += acc[i][3];
        } else {
            Cp[0] = acc[i][0]; Cp[1] = acc[i][1]; Cp[2] = acc[i][2]; Cp[3] = acc[i][3];
        }
    }
}

// ---------------- x_proj split-K: [2048,1024]@[1024,64] -> partials -------------
__global__ __launch_bounds__(256) void xproj_splitk(
    const float* __restrict__ A, const float* __restrict__ B,
    float* __restrict__ part)
{
    __shared__ float As[16][68];
    __shared__ float Bs[16][68];
    const int tid = threadIdx.x;
    const int tx = tid & 15, ty = tid >> 4;
    const int ks = blockIdx.x;
    const int m0 = blockIdx.y << 6;
    const int arow = tid >> 2, ak = (tid & 3) << 2;
    const int bkr = tid >> 4, bcol = (tid & 15) << 2;
    const int kbase = ks << 7;
    const float* Ap = A + (size_t)(m0 + arow) * DI + kbase + ak;
    const float* Bp = B + (size_t)(kbase + bkr) * 64 + bcol;
    float acc[4][4] = {};
    for (int k0 = 0; k0 < 128; k0 += 16) {
        float4 av = *(const float4*)(Ap + k0);
        float4 bv = *(const float4*)(Bp + k0 * 64);
        As[ak + 0][arow] = av.x;
        As[ak + 1][arow] = av.y;
        As[ak + 2][arow] = av.z;
        As[ak + 3][arow] = av.w;
        *(float4*)&Bs[bkr][bcol] = bv;
        __syncthreads();
#pragma unroll
        for (int kk = 0; kk < 16; ++kk) {
            float4 a = *(const float4*)&As[kk][ty << 2];
            float4 b = *(const float4*)&Bs[kk][tx << 2];
            acc[0][0] = fmaf(a.x, b.x, acc[0][0]);
            acc[0][1] = fmaf(a.x, b.y, acc[0][1]);
            acc[0][2] = fmaf(a.x, b.z, acc[0][2]);
            acc[0][3] = fmaf(a.x, b.w, acc[0][3]);
            acc[1][0] = fmaf(a.y, b.x, acc[1][0]);
            acc[1][1] = fmaf(a.y, b.y, acc[1][1]);
            acc[1][2] = fmaf(a.y, b.z, acc[1][2]);
            acc[1][3] = fmaf(a.y, b.w, acc[1][3]);
            acc[2][0] = fmaf(a.z, b.x, acc[2][0]);
            acc[2][1] = fmaf(a.z, b.y, acc[2][1]);
            acc[2][2] = fmaf(a.z, b.z, acc[2][2]);
            acc[2][3] = fmaf(a.z, b.w, acc[2][3]);
            acc[3][0] = fmaf(a.w, b.x, acc[3][0]);
            acc[3][1] = fmaf(a.w, b.y, acc[3][1]);
            acc[3][2] = fmaf(a.w, b.z, acc[3][2]);
            acc[3][3] = fmaf(a.w, b.w, acc[3][3]);
        }
        __syncthreads();
    }
#pragma unroll
    for (int i = 0; i < 4; ++i) {
        float* Cp = part + ((size_t)ks * LSEQ + m0 + (ty << 2) + i) * 64 + (tx << 2);
        Cp[0] = acc[i][0]; Cp[1] = acc[i][1]; Cp[2] = acc[i][2]; Cp[3] = acc[i][3];
    }
}

__global__ __launch_bounds__(256) void xproj_reduce(
    const float* __restrict__ part, float* __restrict__ dbc)
{
    const int idx = blockIdx.x * 256 + threadIdx.x;   // LSEQ*64
    float s = 0.f;
#pragma unroll
    for (int ks = 0; ks < 8; ++ks) s += part[(size_t)ks * LSEQ * 64 + idx];
    dbc[idx] = s;
}

// ---------------- fc1 epilogue: gelu(tmp + b) + coords@Wpos + bpos --------------
__global__ __launch_bounds__(256) void fc1_epi(
    const float* __restrict__ tmp, const float* __restrict__ bfc1,
    const float* __restrict__ coords, const float* __restrict__ Wpos,
    const float* __restrict__ bpos, float* __restrict__ h)
{
    int idx = blockIdx.x * 256 + threadIdx.x;   // L*DM
    int t = idx >> 9, j = idx & 511;
    float v = tmp[idx] + bfc1[j];
    float g = 0.5f * v * (1.f + erff(v * 0.70710678118654752f));
    h[idx] = g + coords[2 * t] * Wpos[j] + coords[2 * t + 1] * Wpos[DM + j] + bpos[j];
}

// ---------------- RMSNorm over last dim (512) -----------------------------------
__global__ __launch_bounds__(256) void rmsnorm_k(
    const float* __restrict__ h, const float* __restrict__ w, float* __restrict__ out)
{
    const int t = blockIdx.x, tid = threadIdx.x;
    float a = h[(size_t)t * DM + tid];
    float b = h[(size_t)t * DM + 256 + tid];
    float ss = a * a + b * b;
#pragma unroll
    for (int off = 1; off < 64; off <<= 1) ss += __shfl_xor(ss, off);
    __shared__ float red[4];
    if ((tid & 63) == 0) red[tid >> 6] = ss;
    __syncthreads();
    float tot = red[0] + red[1] + red[2] + red[3];
    float inv = rsqrtf(tot * (1.f / DM) + 1e-5f);
    out[(size_t)t * DM + tid] = a * inv * w[tid];
    out[(size_t)t * DM + 256 + tid] = b * inv * w[256 + tid];
}

// ---------------- LayerNorm over last dim (512) ---------------------------------
__global__ __launch_bounds__(256) void layernorm_k(
    const float* __restrict__ h, const float* __restrict__ w,
    const float* __restrict__ bb, float* __restrict__ out)
{
    const int t = blockIdx.x, tid = threadIdx.x;
    float a = h[(size_t)t * DM + tid];
    float b = h[(size_t)t * DM + 256 + tid];
    float s = a + b;
#pragma unroll
    for (int off = 1; off < 64; off <<= 1) s += __shfl_xor(s, off);
    __shared__ float red1[4];
    if ((tid & 63) == 0) red1[tid >> 6] = s;
    __syncthreads();
    float mean = (red1[0] + red1[1] + red1[2] + red1[3]) * (1.f / DM);
    float da = a - mean, db = b - mean;
    float vs = da * da + db * db;
#pragma unroll
    for (int off = 1; off < 64; off <<= 1) vs += __shfl_xor(vs, off);
    __shared__ float red2[4];
    if ((tid & 63) == 0) red2[tid >> 6] = vs;
    __syncthreads();
    float var = (red2[0] + red2[1] + red2[2] + red2[3]) * (1.f / DM);
    float inv = rsqrtf(var + 1e-5f);
    out[(size_t)t * DM + tid] = da * inv * w[tid] + bb[tid];
    out[(size_t)t * DM + 256 + tid] = db * inv * w[256 + tid] + bb[256 + tid];
}

// ---------------- causal depthwise conv (k=4) + SiLU ----------------------------
__global__ __launch_bounds__(256) void conv_silu_k(
    const float* __restrict__ xz, const float* __restrict__ cw,
    const float* __restrict__ cb, float* __restrict__ xc)
{
    int idx = blockIdx.x * 256 + threadIdx.x;   // L*DI
    int t = idx >> 10, c = idx & 1023;
    float w0 = cw[c * 4], w1 = cw[c * 4 + 1], w2 = cw[c * 4 + 2], w3 = cw[c * 4 + 3];
    float s = cb[c];
    if (t >= 3) s = fmaf(xz[(size_t)(t - 3) * 2048 + c], w0, s);
    if (t >= 2) s = fmaf(xz[(size_t)(t - 2) * 2048 + c], w1, s);
    if (t >= 1) s = fmaf(xz[(size_t)(t - 1) * 2048 + c], w2, s);
    s = fmaf(xz[(size_t)t * 2048 + c], w3, s);
    xc[idx] = siluf(s);
}

// ---------------- softplus(delta + dtb) in place --------------------------------
__global__ __launch_bounds__(256) void softplus_k(
    float* __restrict__ delta, const float* __restrict__ dtb)
{
    int idx = blockIdx.x * 256 + threadIdx.x;   // L*DI
    int d = idx & 1023;
    float v = delta[idx] + dtb[d];
    delta[idx] = fmaxf(v, 0.f) + log1pf(expf(-fabsf(v)));
}

// ===================== chunked parallel selective scan ==========================
__global__ __launch_bounds__(256) void scan_p1(
    const float* __restrict__ delta, const float* __restrict__ xc,
    const float* __restrict__ dbc, const float* __restrict__ alog,
    float* __restrict__ aprod, float* __restrict__ hfin)
{
    __shared__ float sD[CHUNK][16], sX[CHUNK][16], sB[CHUNK][16];
    const int tid = threadIdx.x;
    const int g = tid >> 4, n = tid & 15;
    const int d0 = blockIdx.x << 4;
    const int c = blockIdx.y;
    const int t0 = c * CHUNK;
    const int d = d0 + g;
    const float An = -expf(alog[d * NST + n]);
    for (int i = tid; i < CHUNK * 16; i += 256) {
        int r = i >> 4, cc = i & 15;
        sD[r][cc] = delta[(size_t)(t0 + r) * DI + d0 + cc];
        sX[r][cc] = xc[(size_t)(t0 + r) * DI + d0 + cc];
        sB[r][cc] = dbc[(size_t)(t0 + r) * 64 + 32 + cc];
    }
    __syncthreads();
    float h = 0.f, ap = 1.f;
    for (int i = 0; i < CHUNK; ++i) {
        float dl = sD[i][g], xv = sX[i][g];
        float a = expf(dl * An);
        h = fmaf(a, h, dl * xv * sB[i][n]);
        ap *= a;
    }
    size_t idx = ((size_t)c * DI + d) * NST + n;
    aprod[idx] = ap;
    hfin[idx] = h;
}

__global__ __launch_bounds__(256) void scan_carry(
    const float* __restrict__ aprod, const float* __restrict__ hfin,
    float* __restrict__ carry)
{
    const int dn = blockIdx.x * 256 + threadIdx.x;   // DI*NST
    float h = 0.f;
    carry[dn] = 0.f;
#pragma unroll
    for (int c = 0; c < NC - 1; ++c) {
        h = fmaf(aprod[(size_t)c * DI * NST + dn], h, hfin[(size_t)c * DI * NST + dn]);
        carry[(size_t)(c + 1) * DI * NST + dn] = h;
    }
}

__global__ __launch_bounds__(256) void scan_p2(
    const float* __restrict__ delta, const float* __restrict__ xc,
    const float* __restrict__ dbc, const float* __restrict__ xz,
    const float* __restrict__ alog, const float* __restrict__ Dp,
    const float* __restrict__ carry, float* __restrict__ y)
{
    __shared__ float sD[CHUNK][16], sX[CHUNK][16], sB[CHUNK][16], sC[CHUNK][16], sZ[CHUNK][16];
    const int tid = threadIdx.x;
    const int g = tid >> 4, n = tid & 15;
    const int d0 = blockIdx.x << 4;
    const int c = blockIdx.y;
    const int t0 = c * CHUNK;
    const int d = d0 + g;
    const float An = -expf(alog[d * NST + n]);
    const float Dd = Dp[d];
    for (int i = tid; i < CHUNK * 16; i += 256) {
        int r = i >> 4, cc = i & 15;
        sD[r][cc] = delta[(size_t)(t0 + r) * DI + d0 + cc];
        sX[r][cc] = xc[(size_t)(t0 + r) * DI + d0 + cc];
        sB[r][cc] = dbc[(size_t)(t0 + r) * 64 + 32 + cc];
        sC[r][cc] = dbc[(size_t)(t0 + r) * 64 + 48 + cc];
        sZ[r][cc] = xz[(size_t)(t0 + r) * 2048 + 1024 + d0 + cc];
    }
    __syncthreads();
    float h = carry[((size_t)c * DI + d) * NST + n];
    for (int i = 0; i < CHUNK; ++i) {
        float dl = sD[i][g], xv = sX[i][g];
        float a = expf(dl * An);
        h = fmaf(a, h, dl * xv * sB[i][n]);
        float p = h * sC[i][n];
        p += __shfl_xor(p, 1, 16);
        p += __shfl_xor(p, 2, 16);
        p += __shfl_xor(p, 4, 16);
        p += __shfl_xor(p, 8, 16);
        if (n == 0) {
            float yv = p + xv * Dd;
            float zz = sZ[i][g];
            y[(size_t)(t0 + i) * DI + d] = yv * siluf(zz);
        }
    }
}

// ---------------- attn epilogue: scores = tanh(amx+ba1)@Wa2 + ba2 ---------------
__global__ __launch_bounds__(256) void attn_fin(
    const float* __restrict__ amx, const float* __restrict__ ba1,
    const float* __restrict__ Wa2, const float* __restrict__ ba2,
    float* __restrict__ scores)
{
    const int tid = threadIdx.x;
    const int row = blockIdx.x * 4 + (tid >> 6);
    const int lane = tid & 63;
    float v = tanhf(amx[(size_t)row * 128 + lane] + ba1[lane]) * Wa2[lane]
            + tanhf(amx[(size_t)row * 128 + 64 + lane] + ba1[64 + lane]) * Wa2[64 + lane];
#pragma unroll
    for (int off = 1; off < 64; off <<= 1) v += __shfl_xor(v, off);
    if (lane == 0) scores[row] = v + ba2[0];
}

// ---------------- softmax over 2048 scores (one block) --------------------------
__global__ __launch_bounds__(1024) void softmax_k(
    const float* __restrict__ s, float* __restrict__ w)
{
    const int tid = threadIdx.x;
    __shared__ float red[16];
    float m = fmaxf(s[tid], s[tid + 1024]);
#pragma unroll
    for (int off = 1; off < 64; off <<= 1) m = fmaxf(m, __shfl_xor(m, off));
    if ((tid & 63) == 0) red[tid >> 6] = m;
    __syncthreads();
    if (tid < 64) {
        float mm = (tid < 16) ? red[tid] : -1e30f;
#pragma unroll
        for (int off = 1; off < 16; off <<= 1) mm = fmaxf(mm, __shfl_xor(mm, off));
        if (tid == 0) red[0] = mm;
    }
    __syncthreads();
    const float gm = red[0];
    __syncthreads();
    float e0 = expf(s[tid] - gm), e1 = expf(s[tid + 1024] - gm);
    float sum = e0 + e1;
#pragma unroll
    for (int off = 1; off < 64; off <<= 1) sum += __shfl_xor(sum, off);
    __shared__ float red2[16];
    if ((tid & 63) == 0) red2[tid >> 6] = sum;
    __syncthreads();
    if (tid < 64) {
        float ss = (tid < 16) ? red2[tid] : 0.f;
#pragma unroll
        for (int off = 1; off < 16; off <<= 1) ss += __shfl_xor(ss, off);
        if (tid == 0) red2[0] = ss;
    }
    __syncthreads();
    float inv = 1.f / red2[0];
    w[tid] = e0 * inv;
    w[tid + 1024] = e1 * inv;
}

// ---------------- pooled: two-stage  part[tc,j] then sum ------------------------
__global__ __launch_bounds__(256) void pooled_p1(
    const float* __restrict__ wts, const float* __restrict__ hf, float* __restrict__ part)
{
    const int j = blockIdx.x * 256 + threadIdx.x;   // 0..511
    const int tc = blockIdx.y;                       // 16 chunks of 128
    float acc = 0.f;
    const int t0 = tc * 128;
    for (int t = t0; t < t0 + 128; ++t) acc = fmaf(wts[t], hf[(size_t)t * DM + j], acc);
    part[(size_t)tc * DM + j] = acc;
}

__global__ __launch_bounds__(256) void pooled_p2(
    const float* __restrict__ part, float* __restrict__ pooled)
{
    const int j = blockIdx.x * 256 + threadIdx.x;
    float acc = 0.f;
#pragma unroll
    for (int tc = 0; tc < 16; ++tc) acc += part[(size_t)tc * DM + j];
    pooled[j] = acc;
}

// ---------------- ct1: ConvT 1x1->4x4 (s=1,p=0), 512->256, relu -----------------
__global__ __launch_bounds__(256) void ct1_fast(
    const float* __restrict__ feat, const float* __restrict__ w,
    const float* __restrict__ b, float* __restrict__ out)
{
    __shared__ float sf[512];
    __shared__ float sRed[256];
    const int o = blockIdx.x, tid = threadIdx.x;
    sf[tid] = feat[tid];
    sf[tid + 256] = feat[tid + 256];
    __syncthreads();
    const int p = tid & 15, g = tid >> 4;
    float acc = 0.f;
#pragma unroll 8
    for (int ci = g * 32; ci < g * 32 + 32; ++ci)
        acc = fmaf(sf[ci], w[ci * 4096 + (o << 4) + p], acc);
    sRed[tid] = acc;
    __syncthreads();
    if (g == 0) {
        float s = b[o];
#pragma unroll
        for (int gg = 0; gg < 16; ++gg) s += sRed[gg * 16 + p];
        out[(o << 4) + p] = fmaxf(s, 0.f);
    }
}

// ---------------- ct2: ConvT 4x4->16x16 (s=4,p=0), 256->128, relu ---------------
__global__ __launch_bounds__(256) void ct2_fast(
    const float* __restrict__ in, const float* __restrict__ w,
    const float* __restrict__ b, float* __restrict__ out)
{
    __shared__ float sI[1024];   // [ci][ix]
    __shared__ float sW[1024];   // [ci][kx]
    __shared__ float sRed[256];
    const int yy = blockIdx.x, o = blockIdx.y, tid = threadIdx.x;
    const int iy = yy >> 2, ky = yy & 3;
    for (int i = tid; i < 1024; i += 256) {
        int ci = i >> 2, q = i & 3;
        sI[i] = in[(ci << 4) + (iy << 2) + q];
        sW[i] = w[ci * 2048 + (o << 4) + (ky << 2) + q];
    }
    __syncthreads();
    const int xx = tid & 15, g = tid >> 4;
    const int ix = xx >> 2, kx = xx & 3;
    float acc = 0.f;
#pragma unroll 8
    for (int ci = g * 16; ci < g * 16 + 16; ++ci)
        acc = fmaf(sI[(ci << 2) + ix], sW[(ci << 2) + kx], acc);
    sRed[tid] = acc;
    __syncthreads();
    if (g == 0) {
        float s = b[o];
#pragma unroll
        for (int gg = 0; gg < 16; ++gg) s += sRed[gg * 16 + xx];
        out[(o << 8) + (yy << 4) + xx] = fmaxf(s, 0.f);
    }
}

// ---------------- ConvT (k=4,s=2,p=1) Hin->2*Hin, LDS-staged --------------------
__global__ __launch_bounds__(256) void ctup_fast(
    const float* __restrict__ in, const float* __restrict__ w,
    const float* __restrict__ b, float* __restrict__ out,
    int Cin, int Cout, int Hin, int hshift, int relu)
{
    __shared__ float sIn[4608];   // 2 rows x Cin x (Hin+2), max 2*128*18
    __shared__ float sW[2048];    // Cin x 16
    __shared__ float sRed[256];
    const int tid = threadIdx.x;
    const int yy = blockIdx.x, o = blockIdx.y;
    const int Hout = Hin << 1;
    const int ST = Hin + 2;
    const int houtshift = hshift + 1;

    const int ky0 = (yy + 1) & 1;
    const int iy0 = (yy + 1 - ky0) >> 1;
    const int iy1 = iy0 - 1;
    const int row_elems = Cin * ST;

    for (int i = tid; i < 2 * row_elems; i += 256) sIn[i] = 0.f;
    __syncthreads();
    const int nload = Cin << hshift;
    if (iy0 < Hin) {
        const float* src = in + ((size_t)iy0 << hshift);
        for (int i = tid; i < nload; i += 256) {
            int ci = i >> hshift, col = i & (Hin - 1);
            sIn[ci * ST + 1 + col] = src[((size_t)ci << (2 * hshift)) + col];
        }
    }
    if (iy1 >= 0) {
        const float* src = in + ((size_t)iy1 << hshift);
        for (int i = tid; i < nload; i += 256) {
            int ci = i >> hshift, col = i & (Hin - 1);
            sIn[row_elems + ci * ST + 1 + col] = src[((size_t)ci << (2 * hshift)) + col];
        }
    }
    for (int i = tid; i < (Cin << 4); i += 256)
        sW[i] = w[(size_t)(i >> 4) * (Cout << 4) + (o << 4) + (i & 15)];
    __syncthreads();

    const int xx = tid & (Hout - 1);
    const int g = tid >> houtshift;
    const int kx0 = (xx + 1) & 1;
    const int ix0 = (xx + 1 - kx0) >> 1;
    const int k00 = (ky0 << 2) + kx0;

    float acc = 0.f;
    const float* in1 = sIn + row_elems;
#pragma unroll 4
    for (int ci = g * 16; ci < g * 16 + 16; ++ci) {
        const int base = ci * ST + ix0;
        const float* wr = &sW[ci << 4];
        float i00 = sIn[base + 1], i01 = sIn[base];
        float i10 = in1[base + 1], i11 = in1[base];
        acc = fmaf(i00, wr[k00], acc);
        acc = fmaf(i01, wr[k00 + 2], acc);
        acc = fmaf(i10, wr[k00 + 8], acc);
        acc = fmaf(i11, wr[k00 + 10], acc);
    }
    sRed[tid] = acc;
    __syncthreads();
    if (g == 0) {
        float s = b[o];
        const int XG = 256 >> houtshift;
        for (int gg = 0; gg < XG; ++gg) s += sRed[(gg << houtshift) + xx];
        out[(size_t)o * Hout * Hout + (size_t)yy * Hout + xx] = relu ? fmaxf(s, 0.f) : s;
    }
}

extern "C" void kernel_launch(void* const* d_in, const int* in_sizes, int n_in,
                              void* d_out, int out_size, void* d_ws, size_t ws_size,
                              hipStream_t stream)
{
    const float* x      = (const float*)d_in[0];
    const float* coords = (const float*)d_in[1];
    const float* Wfc1   = (const float*)d_in[2];
    const float* bfc1   = (const float*)d_in[3];
    const float* Wpos   = (const float*)d_in[4];
    const float* bpos   = (const float*)d_in[5];
    const float* in_w   = (const float*)d_in[6];
    const float* conv_w = (const float*)d_in[7];
    const float* conv_b = (const float*)d_in[8];
    const float* x_w    = (const float*)d_in[9];
    const float* dt_w   = (const float*)d_in[10];
    const float* dt_b   = (const float*)d_in[11];
    const float* A_log  = (const float*)d_in[12];
    const float* Dp     = (const float*)d_in[13];
    const float* out_w  = (const float*)d_in[14];
    const float* rms_w  = (const float*)d_in[15];
    const float* ln_w   = (const float*)d_in[16];
    const float* ln_b   = (const float*)d_in[17];
    const float* Wa1    = (const float*)d_in[18];
    const float* ba1    = (const float*)d_in[19];
    const float* Wa2    = (const float*)d_in[20];
    const float* ba2    = (const float*)d_in[21];
    const float* ct1w   = (const float*)d_in[22];
    const float* ct1b   = (const float*)d_in[23];
    const float* ct2w   = (const float*)d_in[24];
    const float* ct2b   = (const float*)d_in[25];
    const float* ct3w   = (const float*)d_in[26];
    const float* ct3b   = (const float*)d_in[27];
    const float* ct4w   = (const float*)d_in[28];
    const float* ct4b   = (const float*)d_in[29];
    const float* ct5w   = (const float*)d_in[30];
    const float* ct5b   = (const float*)d_in[31];

    // workspace layout (floats)
    float* ws     = (float*)d_ws;
    float* h      = ws;                         // L*DM
    float* hn     = h + (size_t)LSEQ * DM;      // L*DM
    float* xz     = hn + (size_t)LSEQ * DM;     // L*2048 (aliased: fc1/out_proj split-K partials, attn amx)
    float* xc     = xz + (size_t)LSEQ * 2 * DI; // L*DI
    float* dbc    = xc + (size_t)LSEQ * DI;     // L*64
    float* delta  = dbc + (size_t)LSEQ * 64;    // L*DI
    float* yb     = delta + (size_t)LSEQ * DI;  // L*DI (aliased: x_proj split-K partials)
    float* hf     = yb + (size_t)LSEQ * DI;     // L*DM
    float* scores = hf + (size_t)LSEQ * DM;     // L
    float* wts    = scores + LSEQ;              // L
    float* pooled = wts + LSEQ;                 // DM
    float* c1     = pooled + DM;                // 256*16
    float* c2     = c1 + 256 * 16;              // 128*256
    float* c3     = c2 + 128 * 256;             // 64*1024
    float* c4     = c3 + 64 * 1024;             // 32*4096
    float* aprod  = c4 + 32 * 4096;             // NC*DI*NST
    float* hfin   = aprod + (size_t)NC * DI * NST;
    float* carry  = hfin + (size_t)NC * DI * NST;
    float* part   = carry + (size_t)NC * DI * NST;  // 16*DM (pooled partials)
    float* partk  = yb;                          // alias: x_proj split-K partials
    float* skpart = xz;                          // alias: fc1/out_proj split-K partials (4*L*DM = L*2048)
    float* amx    = xz;                          // alias: attn pre-act [L,128]

    // fc1 (split-K=4) + gelu + pos-emb
    gemm_mt<<<dim3(DM / 128, LSEQ / 64, 4), 256, 0, stream>>>(x, 1024, Wfc1, DM, skpart, DM, 1024);
    sk_reduce<<<LSEQ * DM / 256, 256, 0, stream>>>(skpart, hn, LSEQ * DM, 4, 0);
    fc1_epi<<<LSEQ * DM / 256, 256, 0, stream>>>(hn, bfc1, coords, Wpos, bpos, h);

    for (int l = 0; l < 2; ++l) {
        rmsnorm_k<<<LSEQ, 256, 0, stream>>>(h, rms_w + l * DM, hn);
        gemm_mt<<<dim3(2 * DI / 128, LSEQ / 64, 1), 256, 0, stream>>>(
            hn, DM, in_w + (size_t)l * DM * 2 * DI, 2 * DI, xz, 2 * DI, DM);
        conv_silu_k<<<LSEQ * DI / 256, 256, 0, stream>>>(
            xz, conv_w + (size_t)l * DI * 4, conv_b + (size_t)l * DI, xc);
        xproj_splitk<<<dim3(8, LSEQ / 64), 256, 0, stream>>>(
            xc, x_w + (size_t)l * DI * 64, partk);
        xproj_reduce<<<LSEQ * 64 / 256, 256, 0, stream>>>(partk, dbc);
        gemm64<<<dim3(DI / 64, LSEQ / 64), 256, 0, stream>>>(
            dbc, 64, dt_w + (size_t)l * 32 * DI, DI, delta, DI, 32, 0);
        softplus_k<<<LSEQ * DI / 256, 256, 0, stream>>>(delta, dt_b + (size_t)l * DI);
        scan_p1<<<dim3(DI / 16, NC), 256, 0, stream>>>(
            delta, xc, dbc, A_log + (size_t)l * DI * NST, aprod, hfin);
        scan_carry<<<DI * NST / 256, 256, 0, stream>>>(aprod, hfin, carry);
        scan_p2<<<dim3(DI / 16, NC), 256, 0, stream>>>(
            delta, xc, dbc, xz, A_log + (size_t)l * DI * NST, Dp + (size_t)l * DI,
            carry, yb);
        // out_proj split-K=4 into xz partials (xz dead here), then add into h
        gemm_mt<<<dim3(DM / 128, LSEQ / 64, 4), 256, 0, stream>>>(
            yb, DI, out_w + (size_t)l * DI * DM, DM, skpart, DM, 1024);
        sk_reduce<<<LSEQ * DM / 256, 256, 0, stream>>>(skpart, h, LSEQ * DM, 4, 1);
    }

    layernorm_k<<<LSEQ, 256, 0, stream>>>(h, ln_w, ln_b, hf);
    gemm64<<<dim3(2, LSEQ / 64), 256, 0, stream>>>(hf, DM, Wa1, 128, amx, 128, DM, 0);
    attn_fin<<<LSEQ / 4, 256, 0, stream>>>(amx, ba1, Wa2, ba2, scores);
    softmax_k<<<1, 1024, 0, stream>>>(scores, wts);
    pooled_p1<<<dim3(2, 16), 256, 0, stream>>>(wts, hf, part);
    pooled_p2<<<2, 256, 0, stream>>>(part, pooled);

    ct1_fast<<<256, 256, 0, stream>>>(pooled, ct1w, ct1b, c1);
    ct2_fast<<<dim3(16, 128), 256, 0, stream>>>(c1, ct2w, ct2b, c2);
    ctup_fast<<<dim3(32, 64), 256, 0, stream>>>(c2, ct3w, ct3b, c3, 128, 64, 16, 4, 1);
    ctup_fast<<<dim3(64, 32), 256, 0, stream>>>(c3, ct4w, ct4b, c4, 64, 32, 32, 5, 1);
    ctup_fast<<<dim3(128, 11), 256, 0, stream>>>(c4, ct5w, ct5b, (float*)d_out, 32, 11, 64, 6, 0);
}